// Round 20
// baseline (1074.065 us; speedup 1.0000x reference)
//
#include <hip/hip_runtime.h>
#include <hip/hip_bf16.h>
#include <cmath>

#define DEVFN __device__ __forceinline__

constexpr int HW = 16384;                      // 128*128
constexpr long long U = 16777216LL;            // 8*128*16384 floats
constexpr long long NHWC_N = 2163200LL;        // 130*130*128 ushorts per image

typedef __attribute__((ext_vector_type(8))) short bf16x8;
typedef __attribute__((ext_vector_type(4))) float f32x4;
typedef __attribute__((ext_vector_type(4))) unsigned short u16x4;

// ---- workspace layout (floats). B1 = ws[0,U), B2 = ws[U,2U), S = ws[2U,...). ~130 MB. ----
constexpr long long OFF_X1   = 0;
constexpr long long OFF_QS   = U/2;
constexpr long long OFF_KK   = 3*U/4;
constexpr long long OFF_X2O  = U/2;
constexpr long long OFF_V    = U;
constexpr long long OFF_LF   = U + U/4;
constexpr long long OFF_QP   = U + U/2;
constexpr long long OFF_KP   = U + U/2 + 1048576;
constexpr long long S0       = 2*U;
constexpr long long OFF_QKB  = S0;
constexpr long long OFF_AA   = S0 + 8192;
constexpr long long OFF_MQ   = S0 + 16384;
constexpr long long OFF_DQ   = S0 + 17408;
constexpr long long OFF_PMAX = S0 + 18432;     // 131072 (later: bf16 weight packs)
constexpr long long OFF_PSUM = S0 + 149504;    // 131072
constexpr long long OFF_MC   = S0 + 280576;
constexpr long long OFF_DC   = S0 + 281600;
constexpr long long OFF_ATT  = S0 + 282624;    // 131072
constexpr long long OFF_SSL  = S0 + 430080;
constexpr long long OFF_SSH  = S0 + 430336;
constexpr long long OFF_SSY  = S0 + 430592;
constexpr long long OFF_DV   = S0 + 430848;
constexpr long long OFF_D0   = S0 + 432896;
constexpr long long OFF_D1   = S0 + 433920;
constexpr long long OFF_WQK  = S0 + 434944;    // 5120 floats
constexpr long long OFF_WLOW  = OFF_PMAX;
constexpr long long OFF_WHIGH = OFF_PMAX + 73728;
constexpr long long OFF_WOUT  = OFF_PMAX + 147456;
// scratch in d_out tail (floats; NHWC region ends at float 8,652,800)
constexpr long long DOFF_CTXP  = 9000000;      // 8192 floats
constexpr long long DOFF_PARTA = 9100000;      // 262144 floats (1024 blocks x 128 co x 2)
constexpr long long DOFF_PARTB = 9700000;      // 262144

struct Taps { float g[7]; };

DEVFN float gelu_f(float v) { return 0.5f * v * (1.0f + erff(v * 0.7071067811865475f)); }
DEVFN unsigned short f2b(float f) {
  unsigned u = __float_as_uint(f);
  unsigned r = u + 0x7fffu + ((u >> 16) & 1u);
  return (unsigned short)(r >> 16);
}
DEVFN unsigned pk2(float a, float b) {
  return (unsigned)f2b(a) | ((unsigned)f2b(b) << 16);
}

// ---------------- depthwise 3x3 + gelu on even channels ----------------
__global__ __launch_bounds__(256) void k_dwconv(const float* __restrict__ x, const float* __restrict__ w9,
                                                const float* __restrict__ bia, float* __restrict__ out) {
  int g = blockIdx.x * 256 + threadIdx.x;
  int w = g & 127, h = (g >> 7) & 127, c = (g >> 14) & 63, n = g >> 20;
  const float* src = x + (long long)(n * 128 + 2 * c) * HW;
  float acc = bia[c];
  #pragma unroll
  for (int ky = 0; ky < 3; ++ky) {
    int h2 = h + ky - 1;
    if ((unsigned)h2 < 128u) {
      #pragma unroll
      for (int kx = 0; kx < 3; ++kx) {
        int w2 = w + kx - 1;
        if ((unsigned)w2 < 128u) acc = fmaf(w9[c * 9 + ky * 3 + kx], src[h2 * 128 + w2], acc);
      }
    }
  }
  out[(long long)(n * 64 + c) * HW + h * 128 + w] = gelu_f(acc);
}

// ---------------- pack qkvl weights ----------------
__global__ __launch_bounds__(256) void k_wpackq(const float* __restrict__ w, unsigned short* __restrict__ wp) {
  int g = blockIdx.x * 256 + threadIdx.x;
  if (g < 10240) wp[g] = f2b(w[g]);
}

// ---------------- qkvl 1x1 conv (64->160) via bf16 MFMA, 64-px tiles for occupancy ----------------
__global__ __launch_bounds__(256) void k_qkvlm(const float* __restrict__ x, const unsigned short* __restrict__ wqk,
                                               const float* __restrict__ bq, float* __restrict__ qs,
                                               float* __restrict__ kk, float* __restrict__ vv,
                                               float* __restrict__ lf) {
  __shared__ unsigned int Bs[64 * 36];         // 9216 B; reused as [32][68] f32 in epilogue
  const int t = threadIdx.x;
  const int bx = blockIdx.x, n = blockIdx.y;   // bx in [0,256)
  const int pxb = bx * 64;
  #pragma unroll
  for (int it = 0; it < 8; ++it) {
    int e = it * 256 + t;
    int px = e & 63, k2 = e >> 6;
    float v0 = x[(long long)(n * 128 + 4 * k2 + 1) * HW + pxb + px];
    float v1 = x[(long long)(n * 128 + 4 * k2 + 3) * HW + pxb + px];
    Bs[px * 36 + k2] = pk2(v0, v1);
  }
  __syncthreads();
  const int wid = t >> 6, lane = t & 63, l15 = lane & 15, l4 = lane >> 4;
  f32x4 acc[10];
  #pragma unroll
  for (int m = 0; m < 10; ++m) { f32x4 z = {0.f,0.f,0.f,0.f}; acc[m] = z; }
  #pragma unroll
  for (int ks = 0; ks < 2; ++ks) {
    bf16x8 bfr = *(const bf16x8*)(&Bs[(wid * 16 + l15) * 36 + ks * 16 + l4 * 4]);
    #pragma unroll
    for (int mf = 0; mf < 10; ++mf) {
      bf16x8 af = *(const bf16x8*)(wqk + (mf * 16 + l15) * 64 + ks * 32 + l4 * 8);
      acc[mf] = __builtin_amdgcn_mfma_f32_16x16x32_bf16(af, bfr, acc[mf], 0, 0, 0);
    }
  }
  float* sT = (float*)Bs;                      // [32][68]
  const int pxl = wid * 16 + l15;
  const int jo = t >> 3, p0 = (t & 7) * 8;
  #pragma unroll
  for (int tau = 0; tau < 4; ++tau) {
    __syncthreads();
    #pragma unroll
    for (int mf = 0; mf < 2; ++mf) {
      #pragma unroll
      for (int r = 0; r < 4; ++r) {
        int j = mf * 16 + l4 * 4 + r;
        float v;
        if (tau == 0)
          v = gelu_f(acc[mf][r] + bq[j]) + gelu_f(acc[mf + 2][r] + bq[32 + j]);
        else
          v = gelu_f(acc[2 + 2 * tau + mf][r] + bq[32 * (tau + 1) + j]);
        sT[j * 68 + pxl] = v;
      }
    }
    __syncthreads();
    float* dstp = (tau == 0) ? qs : (tau == 1) ? kk : (tau == 2) ? vv : lf;
    long long o = (long long)(n * 32 + jo) * HW + pxb + p0;
    #pragma unroll
    for (int q4 = 0; q4 < 2; ++q4)
      *(f32x4*)&dstp[o + q4 * 4] = *(const f32x4*)&sT[jo * 68 + p0 + q4 * 4];
  }
}

// ---------------- pools ----------------
__global__ __launch_bounds__(256) void k_avgpool(const float* __restrict__ in, float* __restrict__ out) {
  int g = blockIdx.x * 256 + threadIdx.x;
  int ow = g & 63, oh = (g >> 6) & 63, c = (g >> 12) & 31, n = g >> 17;
  const float* src = in + (long long)(n * 32 + c) * HW;
  float s = 0.f;
  #pragma unroll
  for (int i = 0; i < 3; ++i) {
    int h = oh * 2 - 1 + i;
    if ((unsigned)h < 128u) {
      #pragma unroll
      for (int j = 0; j < 3; ++j) {
        int w = ow * 2 - 1 + j;
        if ((unsigned)w < 128u) s += src[h * 128 + w];
      }
    }
  }
  out[(long long)(n * 32 + c) * 4096 + oh * 64 + ow] = s * (1.f / 9.f);
}

__global__ __launch_bounds__(256) void k_maxpool(const float* __restrict__ in, float* __restrict__ out) {
  int g = blockIdx.x * 256 + threadIdx.x;
  int ow = g & 63, oh = (g >> 6) & 63, c = (g >> 12) & 31, n = g >> 17;
  const float* src = in + (long long)(n * 32 + c) * HW;
  float m = -3.0e38f;
  #pragma unroll
  for (int i = 0; i < 2; ++i)
    #pragma unroll
    for (int j = 0; j < 2; ++j)
      m = fmaxf(m, src[(oh * 2 + i) * 128 + ow * 2 + j]);
  out[(long long)(n * 32 + c) * 4096 + oh * 64 + ow] = m;
}

// ---------------- qk (32x32 per n, K=4096) ----------------
__global__ __launch_bounds__(256) void k_qk(const float* __restrict__ qp, const float* __restrict__ kp,
                                            float* __restrict__ qk) {
  int c = blockIdx.x, n = blockIdx.y;
  int t = threadIdx.x, d = t >> 3, r = t & 7;
  const float* qr = qp + (long long)(n * 32 + c) * 4096;
  const float* kr = kp + (long long)(n * 32 + d) * 4096;
  float acc = 0.f;
  for (int p = r; p < 4096; p += 8) acc = fmaf(qr[p], kr[p], acc);
  acc += __shfl_down(acc, 4, 8);
  acc += __shfl_down(acc, 2, 8);
  acc += __shfl_down(acc, 1, 8);
  if (r == 0) qk[(n * 32 + c) * 32 + d] = acc;
}

__global__ void k_qksm(const float* __restrict__ qk, float* __restrict__ A) {
  int n = blockIdx.x, d = threadIdx.x;
  float m = -3.0e38f;
  for (int c = 0; c < 32; ++c) m = fmaxf(m, qk[(n * 32 + c) * 32 + d]);
  float s = 0.f;
  for (int c = 0; c < 32; ++c) s += expf(qk[(n * 32 + c) * 32 + d] - m);
  float inv = 1.f / s;
  for (int c = 0; c < 32; ++c) A[(n * 32 + c) * 32 + d] = expf(qk[(n * 32 + c) * 32 + d] - m) * inv;
}

// ---------------- x2o = A^T @ v ----------------
__global__ __launch_bounds__(256) void k_x2o(const float* __restrict__ A, const float* __restrict__ vsrc,
                                             float* __restrict__ out) {
  __shared__ float lA[1024];
  int t = threadIdx.x;
  int g = blockIdx.x * 256 + t;
  int n = g >> 14, p = g & 16383;
  for (int e = t; e < 1024; e += 256) lA[e] = A[n * 1024 + e];
  __syncthreads();
  float acc[32];
  #pragma unroll
  for (int i = 0; i < 32; ++i) acc[i] = 0.f;
  for (int q = 0; q < 32; ++q) {
    float vv = vsrc[(long long)(n * 32 + q) * HW + p];
    #pragma unroll
    for (int k2 = 0; k2 < 32; ++k2) acc[k2] = fmaf(lA[q * 32 + k2], vv, acc[k2]);
  }
  #pragma unroll
  for (int k2 = 0; k2 < 32; ++k2) out[(long long)(n * 32 + k2) * HW + p] = acc[k2];
}

// ---------------- 128x128x128 GEMMs via bf16 MFMA ----------------
enum { M_EFF = 0, M_QX = 1, M_OUT = 2, M_FREQ = 3 };

template <int MODE>
__global__ __launch_bounds__(256) void k_gemm1x1m(
    const float* __restrict__ Amat, const float* __restrict__ B0, const float* __restrict__ B1,
    const float* __restrict__ B2, const float* __restrict__ bias, const float* __restrict__ scale,
    const float* __restrict__ Mq, const float* __restrict__ invDq, const float* __restrict__ xres,
    void* __restrict__ outp) {
  __shared__ unsigned int As[128 * 36];
  __shared__ unsigned int Bs[128 * 36];
  const int t = threadIdx.x;
  const int bx = blockIdx.x, n = blockIdx.y;
  const int pxb = bx * 128;
  const int wid = t >> 6, lane = t & 63, l15 = lane & 15, l4 = lane >> 4;
  const int wy = wid >> 1, wx = wid & 1;
  f32x4 acc[4][4];
  #pragma unroll
  for (int i = 0; i < 4; ++i)
    #pragma unroll
    for (int j = 0; j < 4; ++j) { f32x4 z = {0.f,0.f,0.f,0.f}; acc[i][j] = z; }

  for (int kc = 0; kc < 2; ++kc) {
    __syncthreads();
    if (MODE == M_FREQ) {
      #pragma unroll
      for (int it = 0; it < 16; ++it) {
        int e = it * 256 + t;
        int i = e & 127, j2l = e >> 7;
        int j = kc * 64 + 2 * j2l;
        float v0 = Amat[(long long)(n * 128 + j) * 128 + i];
        float v1 = Amat[(long long)(n * 128 + j + 1) * 128 + i];
        As[i * 36 + j2l] = pk2(v0, v1);
      }
    } else {
      #pragma unroll
      for (int it = 0; it < 16; ++it) {
        int e = it * 256 + t;
        int m = e >> 5, k2l = e & 31;
        float2 v = *(const float2*)(&Amat[m * 128 + kc * 64 + 2 * k2l]);
        As[m * 36 + k2l] = pk2(v.x, v.y);
      }
    }
    if (MODE == M_FREQ) {
      #pragma unroll
      for (int it = 0; it < 16; ++it) {
        int e = it * 256 + t;
        int j2l = e & 31, px = e >> 5;
        int j = kc * 64 + 2 * j2l;
        long long qb = ((long long)n * HW + pxb + px) * 128 + j;
        float2 v = *(const float2*)(&B0[qb]);
        float e0 = expf(v.x - Mq[n * 128 + j]) * invDq[n * 128 + j];
        float e1 = expf(v.y - Mq[n * 128 + j + 1]) * invDq[n * 128 + j + 1];
        Bs[px * 36 + j2l] = pk2(e0, e1);
      }
    } else {
      #pragma unroll
      for (int it = 0; it < 16; ++it) {
        int e = it * 256 + t;
        int px = e & 127, k2l = e >> 7;
        int ci = kc * 64 + 2 * k2l;
        float v0, v1;
        if (MODE == M_EFF) {
          if (ci < 64) {
            v0 = B0[(long long)(n * 64 + ci) * HW + pxb + px];
            v1 = B0[(long long)(n * 64 + ci + 1) * HW + pxb + px];
          } else if (ci < 96) {
            v0 = B1[(long long)(n * 32 + ci - 64) * HW + pxb + px];
            v1 = B1[(long long)(n * 32 + ci - 63) * HW + pxb + px];
          } else {
            v0 = B2[(long long)(n * 32 + ci - 96) * HW + pxb + px];
            v1 = B2[(long long)(n * 32 + ci - 95) * HW + pxb + px];
          }
        } else if (MODE == M_QX) {
          v0 = B0[(long long)(n * 128 + ci) * HW + pxb + px];
          v1 = B0[(long long)(n * 128 + ci + 1) * HW + pxb + px];
        } else {
          float u0 = B0[(long long)(n * 128 + ci) * HW + pxb + px];
          float u1 = B0[(long long)(n * 128 + ci + 1) * HW + pxb + px];
          v0 = fmaxf(fmaf(u0, scale[ci], scale[128 + ci]), 0.f);
          v1 = fmaxf(fmaf(u1, scale[ci + 1], scale[128 + ci + 1]), 0.f);
        }
        Bs[px * 36 + k2l] = pk2(v0, v1);
      }
    }
    __syncthreads();
    #pragma unroll
    for (int ks = 0; ks < 2; ++ks) {
      bf16x8 af[4], bfr[4];
      #pragma unroll
      for (int mf = 0; mf < 4; ++mf)
        af[mf] = *(const bf16x8*)(&As[(wy * 64 + mf * 16 + l15) * 36 + ks * 16 + l4 * 4]);
      #pragma unroll
      for (int nf = 0; nf < 4; ++nf)
        bfr[nf] = *(const bf16x8*)(&Bs[(wx * 64 + nf * 16 + l15) * 36 + ks * 16 + l4 * 4]);
      #pragma unroll
      for (int mf = 0; mf < 4; ++mf)
        #pragma unroll
        for (int nf = 0; nf < 4; ++nf)
          acc[mf][nf] = __builtin_amdgcn_mfma_f32_16x16x32_bf16(af[mf], bfr[nf], acc[mf][nf], 0, 0, 0);
    }
  }
  if (MODE == M_EFF || MODE == M_FREQ) {
    unsigned short* oT = (unsigned short*)outp;
    #pragma unroll
    for (int nf = 0; nf < 4; ++nf) {
      int px = pxb + wx * 64 + nf * 16 + l15;
      int hh = px >> 7, wwp = (px & 127) + 1;
      long long rb = (long long)n * NHWC_N + ((long long)(hh + 1) * 130 + wwp) * 128;
      #pragma unroll
      for (int mf = 0; mf < 4; ++mf) {
        int ch = wy * 64 + mf * 16 + l4 * 4;
        u16x4 pk;
        #pragma unroll
        for (int r = 0; r < 4; ++r) {
          float v = acc[mf][nf][r] + ((MODE == M_EFF) ? bias[ch + r] : 0.f);
          if (MODE == M_FREQ) v += xres[(long long)(n * 128 + ch + r) * HW + px];
          pk[r] = f2b(v);
        }
        *(u16x4*)(&oT[rb + ch]) = pk;
      }
    }
  } else {
    float* of = (float*)outp;
    #pragma unroll
    for (int mf = 0; mf < 4; ++mf)
      #pragma unroll
      for (int nf = 0; nf < 4; ++nf) {
        int px = pxb + wx * 64 + nf * 16 + l15;
        #pragma unroll
        for (int r = 0; r < 4; ++r) {
          int ch = wy * 64 + mf * 16 + l4 * 4 + r;
          of[(long long)(n * 128 + ch) * HW + px] = acc[mf][nf][r] + bias[ch];
        }
      }
  }
}

// ---------------- qx softmax stats (fused max+sum, then cross-c reduce) ----------------
__global__ __launch_bounds__(128) void k_qx_stat1(const float* __restrict__ qx, float* __restrict__ pm,
                                                  float* __restrict__ ps) {
  int c = blockIdx.x, n = blockIdx.y, w = threadIdx.x;
  long long base = (long long)(n * 128 + c) * HW + w;
  float m = -3.0e38f;
  for (int h = 0; h < 128; ++h) m = fmaxf(m, qx[base + h * 128]);
  float s = 0.f;
  for (int h = 0; h < 128; ++h) s += expf(qx[base + h * 128] - m);
  pm[(n * 128 + c) * 128 + w] = m;
  ps[(n * 128 + c) * 128 + w] = s;
}
__global__ __launch_bounds__(128) void k_qx_stat2(const float* __restrict__ pm, const float* __restrict__ ps,
                                                  float* __restrict__ Mq, float* __restrict__ Dq) {
  int n = blockIdx.x, w = threadIdx.x;
  float M = -3.0e38f;
  for (int c = 0; c < 128; ++c) M = fmaxf(M, pm[(n * 128 + c) * 128 + w]);
  float D = 0.f;
  for (int c = 0; c < 128; ++c) D += ps[(n * 128 + c) * 128 + w] * expf(pm[(n * 128 + c) * 128 + w] - M);
  Mq[n * 128 + w] = M;
  Dq[n * 128 + w] = 1.f / D;
}

// ---------------- fused 3-stage gaussian pyramid + ctx + online softmax partials ----------------
constexpr int BROWS = 44;
constexpr int BSTR  = 144;

template <int R, int HLO, int HHI, int VLO, int VHI>
DEVFN void blur_stage4(float* sA, float* sB, const float* __restrict__ g, int h0, int t) {
  __syncthreads();
  constexpr int HN = (HHI - HLO + 1) * 32;
  for (int e = t; e < HN; e += 256) {
    int r = HLO + (e >> 5), g4 = e & 31;
    int base = r * BSTR + 8 + g4 * 4;
    f32x4 a = *(const f32x4*)&sA[base - 4];
    f32x4 b = *(const f32x4*)&sA[base];
    f32x4 c = *(const f32x4*)&sA[base + 4];
    float m[12] = {a[0], a[1], a[2], a[3], b[0], b[1], b[2], b[3], c[0], c[1], c[2], c[3]};
    f32x4 s;
    #pragma unroll
    for (int j = 0; j < 4; ++j) {
      float acc = 0.f;
      #pragma unroll
      for (int d = -R; d <= R; ++d) acc = fmaf(g[d + R], m[4 + j + d], acc);
      s[j] = acc;
    }
    *(f32x4*)&sB[base] = s;
  }
  __syncthreads();
  constexpr int VN = (VHI - VLO + 1) * 32;
  for (int e = t; e < VN; e += 256) {
    int r = VLO + (e >> 5), g4 = e & 31;
    int base = r * BSTR + 8 + g4 * 4;
    f32x4 s = {0.f, 0.f, 0.f, 0.f};
    #pragma unroll
    for (int d = -R; d <= R; ++d) {
      f32x4 v = *(const f32x4*)&sB[base + d * BSTR];
      #pragma unroll
      for (int j = 0; j < 4; ++j) s[j] = fmaf(g[d + R], v[j], s[j]);
    }
    int h = h0 - 6 + r;
    if ((unsigned)h >= 128u) { f32x4 z = {0.f, 0.f, 0.f, 0.f}; s = z; }
    *(f32x4*)&sA[base] = s;
  }
}

__global__ __launch_bounds__(256) void k_blur3(const float* __restrict__ x, float* __restrict__ ctx,
                                               float* __restrict__ ctxp, Taps t3, Taps t5, Taps t7) {
  __shared__ float sA[BROWS * BSTR];
  __shared__ float sB[BROWS * BSTR];
  __shared__ float rm[256], rs[256];
  const int t = threadIdx.x;
  const int ht = blockIdx.x, h0 = ht * 32;
  const long long nc = blockIdx.y;
  const float* src = x + nc * HW;
  for (int e = t; e < BROWS * BSTR; e += 256) {
    int r = e / BSTR, wp = e % BSTR;
    int w = wp - 8, h = h0 - 6 + r;
    sA[e] = ((unsigned)h < 128u && (unsigned)w < 128u) ? src[h * 128 + w] : 0.f;
  }
  blur_stage4<1, 0, 43, 1, 42>(sA, sB, t3.g, h0, t);
  blur_stage4<2, 1, 42, 3, 40>(sA, sB, t5.g, h0, t);
  blur_stage4<3, 3, 40, 6, 37>(sA, sB, t7.g, h0, t);
  __syncthreads();
  long long ob = nc * HW + (long long)h0 * 128;
  float lm = -3.0e38f, lsum = 0.f;
  for (int e = t; e < 1024; e += 256) {
    int r = e >> 5, g4 = e & 31;
    f32x4 xs = *(const f32x4*)&src[(h0 + r) * 128 + g4 * 4];
    f32x4 bl = *(const f32x4*)&sA[(6 + r) * BSTR + 8 + g4 * 4];
    f32x4 v;
    #pragma unroll
    for (int j = 0; j < 4; ++j) {
      v[j] = xs[j] - bl[j];
      float val = v[j];
      if (val > lm) { lsum = lsum * expf(lm - val) + 1.f; lm = val; }
      else lsum += expf(val - lm);
    }
    *(f32x4*)&ctx[ob + r * 128 + g4 * 4] = v;
  }
  rm[t] = lm; rs[t] = lsum; __syncthreads();
  for (int o = 128; o > 0; o >>= 1) {
    if (t < o) {
      float m2 = rm[t + o], s2 = rs[t + o];
      float M = fmaxf(rm[t], m2);
      rs[t] = rs[t] * expf(rm[t] - M) + s2 * expf(m2 - M);
      rm[t] = M;
    }
    __syncthreads();
  }
  if (t == 0) { ctxp[nc * 8 + ht * 2] = rm[0]; ctxp[nc * 8 + ht * 2 + 1] = rs[0]; }
}

__global__ __launch_bounds__(256) void k_ctx_red(const float* __restrict__ ctxp, float* __restrict__ Mc,
                                                 float* __restrict__ Dc) {
  int g = blockIdx.x * 256 + threadIdx.x;   // 1024
  float M = -3.0e38f, S = 0.f;
  #pragma unroll
  for (int i = 0; i < 4; ++i) {
    float m2 = ctxp[g * 8 + i * 2], s2 = ctxp[g * 8 + i * 2 + 1];
    float Mn = fmaxf(M, m2);
    S = S * expf(M - Mn) + s2 * expf(m2 - Mn);
    M = Mn;
  }
  Mc[g] = M; Dc[g] = 1.f / S;
}

// ---------------- att = softmax(ctx) @ ctx^T via bf16 MFMA (partials) ----------------
__global__ __launch_bounds__(256) void k_attm(const float* __restrict__ ctx, const float* __restrict__ Mc,
                                              const float* __restrict__ invDc, float* __restrict__ attp) {
  __shared__ unsigned int As[128 * 36];
  __shared__ unsigned int Bs[128 * 36];
  const int t = threadIdx.x, sp = blockIdx.x, n = blockIdx.y;
  const int wid = t >> 6, lane = t & 63, l15 = lane & 15, l4 = lane >> 4;
  const int wy = wid >> 1, wx = wid & 1;
  f32x4 acc[4][4];
  #pragma unroll
  for (int i = 0; i < 4; ++i)
    #pragma unroll
    for (int j = 0; j < 4; ++j) { f32x4 z = {0.f,0.f,0.f,0.f}; acc[i][j] = z; }
  for (int kc = 0; kc < 8; ++kc) {
    __syncthreads();
    int pb = sp * 512 + kc * 64;
    #pragma unroll
    for (int it = 0; it < 16; ++it) {
      int e = it * 256 + t;
      int row = e >> 5, p2 = e & 31;
      float2 v = *(const float2*)(&ctx[(long long)(n * 128 + row) * HW + pb + 2 * p2]);
      float m = Mc[n * 128 + row], d = invDc[n * 128 + row];
      Bs[row * 36 + p2] = pk2(v.x, v.y);
      As[row * 36 + p2] = pk2(expf(v.x - m) * d, expf(v.y - m) * d);
    }
    __syncthreads();
    #pragma unroll
    for (int ks = 0; ks < 2; ++ks) {
      bf16x8 af[4], bfr[4];
      #pragma unroll
      for (int mf = 0; mf < 4; ++mf)
        af[mf] = *(const bf16x8*)(&As[(wy * 64 + mf * 16 + l15) * 36 + ks * 16 + l4 * 4]);
      #pragma unroll
      for (int nf = 0; nf < 4; ++nf)
        bfr[nf] = *(const bf16x8*)(&Bs[(wx * 64 + nf * 16 + l15) * 36 + ks * 16 + l4 * 4]);
      #pragma unroll
      for (int mf = 0; mf < 4; ++mf)
        #pragma unroll
        for (int nf = 0; nf < 4; ++nf)
          acc[mf][nf] = __builtin_amdgcn_mfma_f32_16x16x32_bf16(af[mf], bfr[nf], acc[mf][nf], 0, 0, 0);
    }
  }
  long long ob = (long long)(sp * 8 + n) * 16384;
  #pragma unroll
  for (int mf = 0; mf < 4; ++mf)
    #pragma unroll
    for (int nf = 0; nf < 4; ++nf) {
      int d = wx * 64 + nf * 16 + l15;
      #pragma unroll
      for (int r = 0; r < 4; ++r) {
        int c = wy * 64 + mf * 16 + l4 * 4 + r;
        attp[ob + c * 128 + d] = acc[mf][nf][r];
      }
    }
}

__global__ __launch_bounds__(256) void k_attred(const float* __restrict__ attp, float* __restrict__ att) {
  int g = blockIdx.x * 256 + threadIdx.x;
  float s = 0.f;
  for (int sp = 0; sp < 32; ++sp) s += attp[(long long)sp * 131072 + g];
  att[g] = s;
}

// ---------------- pack conv weight -> bf16 [co][tap*128+ci] ----------------
__global__ __launch_bounds__(256) void k_wpack(const float* __restrict__ w, unsigned short* __restrict__ wp) {
  int g = blockIdx.x * 256 + threadIdx.x;
  int ci = g & 127;
  int tap = (g >> 7) % 9;
  int co = g / 1152;
  wp[g] = f2b(w[co * 1152 + ci * 9 + tap]);
}

// ---------------- zero halo of padded NHWC bf16 ----------------
__global__ __launch_bounds__(256) void k_haloz(unsigned short* __restrict__ p) {
  int idx = blockIdx.x * 256 + threadIdx.x;
  if (idx >= 66048) return;
  int n = idx / 8256;
  int r = idx % 8256;
  int cell = r >> 4, q = r & 15;
  int h, w;
  if (cell < 130)      { h = 0;   w = cell; }
  else if (cell < 260) { h = 129; w = cell - 130; }
  else if (cell < 388) { h = cell - 260 + 1; w = 0; }
  else                 { h = cell - 388 + 1; w = 129; }
  uint4 z = {0u, 0u, 0u, 0u};
  *(uint4*)(p + (long long)n * NHWC_N + ((long long)h * 130 + w) * 128 + q * 8) = z;
}

// ---------------- 3x3 conv: 2-row x 64-px tiles, bf16 MFMA, gload_lds dbuf, slot-swizzled LDS,
// ---------------- weights register-hoisted per kc (afr[9][4], loaded under the stage drain) ----------------
__global__ __launch_bounds__(256) void k_conv3l(const unsigned short* __restrict__ inT,
                                                const unsigned short* __restrict__ wp,
                                                float* __restrict__ out,
                                                float* __restrict__ part) {
  __shared__ unsigned short Bs[2 * 8448];      // 33792 B
  const int t = threadIdx.x;
  const int bx = blockIdx.x, n = blockIdx.y;   // bx in [0,128)
  const int h0 = (bx >> 1) * 2, w0 = (bx & 1) * 64;
  const int wid = t >> 6, lane = t & 63;
  const int wy = wid >> 1, wx = wid & 1;
  const int l15 = lane & 15, l4 = lane >> 4;
  f32x4 acc[4][2][2];
  #pragma unroll
  for (int i = 0; i < 4; ++i)
    #pragma unroll
    for (int j = 0; j < 2; ++j)
      #pragma unroll
      for (int ro = 0; ro < 2; ++ro) { f32x4 z = {0.f, 0.f, 0.f, 0.f}; acc[i][j][ro] = z; }
  const unsigned short* abase = wp + (wy * 64 + l15) * 1152 + l4 * 8;

  // stage one kc-chunk (1056 16B-chunks: 4 rows x 66 w x 4 slots) into Bs[buf], source-swizzled
  auto STAGE = [&](int kc, int buf) {
    const unsigned short* gb = inT + (long long)n * NHWC_N + kc * 32;
    #pragma unroll
    for (int it = 0; it < 5; ++it) {
      int cbase = it * 256 + wid * 64;
      int c = cbase + lane;
      if (c < 1056) {
        int row = c / 264, rem = c % 264;
        int w = rem >> 2, slot = rem & 3;
        int sg = slot ^ ((w >> 1) & 3);
        const unsigned short* src = gb + ((long long)(h0 + row) * 130 + (w0 + w)) * 128 + sg * 8;
        __builtin_amdgcn_global_load_lds(
            (const __attribute__((address_space(1))) unsigned int*)src,
            (__attribute__((address_space(3))) unsigned int*)&Bs[buf * 8448 + cbase * 8],
            16, 0, 0);
      }
    }
  };

  // weight fragments for the current kc, fully register-resident (144 VGPR)
  bf16x8 afr[9][4];
  auto WLOAD = [&](int kc) {
    #pragma unroll
    for (int tap = 0; tap < 9; ++tap)
      #pragma unroll
      for (int cf = 0; cf < 4; ++cf)
        afr[tap][cf] = *(const bf16x8*)(abase + cf * 16 * 1152 + tap * 128 + kc * 32);
  };

  STAGE(0, 0);
  WLOAD(0);
  #pragma unroll
  for (int kc = 0; kc < 4; ++kc) {
    __syncthreads();                            // drains STAGE(kc) + WLOAD(kc)
    if (kc < 3) STAGE(kc + 1, (kc + 1) & 1);
    const int lb = (kc & 1) * 8448;
    #pragma unroll
    for (int ky = 0; ky < 3; ++ky) {
      #pragma unroll
      for (int kx = 0; kx < 3; ++kx) {
        const int tap = ky * 3 + kx;
        bf16x8 bfr[2][2];
        #pragma unroll
        for (int pf = 0; pf < 2; ++pf) {
          int w = wx * 32 + pf * 16 + l15 + kx;
          int sr = l4 ^ ((w >> 1) & 3);
          #pragma unroll
          for (int ro = 0; ro < 2; ++ro)
            bfr[pf][ro] = *(const bf16x8*)(&Bs[lb + (ro + ky) * 2112 + w * 32 + sr * 8]);
        }
        #pragma unroll
        for (int cf = 0; cf < 4; ++cf)
          #pragma unroll
          for (int pf = 0; pf < 2; ++pf)
            #pragma unroll
            for (int ro = 0; ro < 2; ++ro)
              acc[cf][pf][ro] = __builtin_amdgcn_mfma_f32_16x16x32_bf16(afr[tap][cf], bfr[pf][ro], acc[cf][pf][ro], 0, 0, 0);
      }
    }
    if (kc < 3) WLOAD(kc + 1);                  // L2 latency hides under next barrier's stage drain
  }
  #pragma unroll
  for (int ro = 0; ro < 2; ++ro) {
    long long ob = (long long)n * 128 * HW + (h0 + ro) * 128 + w0;
    #pragma unroll
    for (int cf = 0; cf < 4; ++cf)
      #pragma unroll
      for (int pf = 0; pf < 2; ++pf) {
        int co = wy * 64 + cf * 16 + l4 * 4;
        int wpx = wx * 32 + pf * 16 + l15;
        #pragma unroll
        for (int r = 0; r < 4; ++r)
          out[ob + (long long)(co + r) * HW + wpx] = acc[cf][pf][ro][r];
      }
  }
  // BN partials: per-co sum / sumsq over this block's 128 px (2 rows x 64 w)
  __shared__ float redS[4][64], redQ[4][64];
  #pragma unroll
  for (int cf = 0; cf < 4; ++cf)
    #pragma unroll
    for (int r = 0; r < 4; ++r) {
      float s = 0.f, q = 0.f;
      #pragma unroll
      for (int pf = 0; pf < 2; ++pf)
        #pragma unroll
        for (int ro = 0; ro < 2; ++ro) { float v = acc[cf][pf][ro][r]; s += v; q = fmaf(v, v, q); }
      #pragma unroll
      for (int off = 1; off < 16; off <<= 1) { s += __shfl_xor(s, off, 16); q += __shfl_xor(q, off, 16); }
      if (l15 == 0) { redS[wid][cf * 16 + l4 * 4 + r] = s; redQ[wid][cf * 16 + l4 * 4 + r] = q; }
    }
  __syncthreads();
  if (t < 128) {
    int wy2 = t >> 6, col = t & 63;
    int co = wy2 * 64 + col;
    float s = redS[wy2 * 2][col] + redS[wy2 * 2 + 1][col];
    float q = redQ[wy2 * 2][col] + redQ[wy2 * 2 + 1][col];
    long long pb = ((long long)(n * 128 + bx) * 128 + co) * 2;
    part[pb] = s; part[pb + 1] = q;
  }
}

// ---------------- BN reduce over 1024 block-partials ----------------
__global__ __launch_bounds__(256) void k_bnred(const float* __restrict__ part, const float* __restrict__ g,
                                               const float* __restrict__ bb, float* __restrict__ ssout) {
  int c = blockIdx.x, t = threadIdx.x;
  float s = 0.f, q = 0.f;
  for (int b = t; b < 1024; b += 256) {
    s += part[((long long)b * 128 + c) * 2];
    q += part[((long long)b * 128 + c) * 2 + 1];
  }
  __shared__ float r1[256], r2[256];
  r1[t] = s; r2[t] = q; __syncthreads();
  for (int o = 128; o > 0; o >>= 1) { if (t < o) { r1[t] += r1[t + o]; r2[t] += r2[t + o]; } __syncthreads(); }
  if (t == 0) {
    float mean = r1[0] / 131072.f;
    float var = r2[0] / 131072.f - mean * mean;
    float sc = g[c] * rsqrtf(var + 1e-5f);
    ssout[c] = sc;
    ssout[128 + c] = bb[c] - mean * sc;
  }
}

// ---------------- cubic power-mean per (n,c) ----------------
__global__ __launch_bounds__(256) void k_power(const float* __restrict__ in, const float* __restrict__ ss,
                                               float* __restrict__ dst, int off) {
  int c = blockIdx.x, n = blockIdx.y, t = threadIdx.x;
  float sc = ss[c], sh = ss[128 + c];
  long long base = (long long)(n * 128 + c) * HW;
  float s = 0.f;
  for (int i = t; i < HW; i += 256) {
    float r = fmaxf(fmaf(in[base + i], sc, sh), 0.f);
    s += r * r * r;
  }
  __shared__ float red[256];
  red[t] = s; __syncthreads();
  for (int o = 128; o > 0; o >>= 1) { if (t < o) red[t] += red[t + o]; __syncthreads(); }
  if (t == 0) dst[n * 256 + 2 * c + off] = cbrtf(red[0] * (1.f / 16384.f) + 1e-12f);
}

// ---------------- 1d conv x2 + sigmoid ----------------
__global__ __launch_bounds__(256) void k_dvec(const float* __restrict__ din, const float* __restrict__ c1,
                                              const float* __restrict__ c2, float* __restrict__ d0,
                                              float* __restrict__ d1) {
  __shared__ float a[256], b[256];
  int n = blockIdx.x, t = threadIdx.x;
  a[t] = din[n * 256 + t];
  __syncthreads();
  float acc = 0.f;
  #pragma unroll
  for (int k = 0; k < 5; ++k) { int j = t + k - 2; if (0 <= j && j < 256) acc = fmaf(c1[k], a[j], acc); }
  b[t] = acc; __syncthreads();
  float acc2 = 0.f;
  #pragma unroll
  for (int k = 0; k < 5; ++k) { int j = t + k - 2; if (0 <= j && j < 256) acc2 = fmaf(c2[k], b[j], acc2); }
  float sg = 1.f / (1.f + expf(-acc2));
  if ((t & 1) == 0) d0[n * 128 + (t >> 1)] = sg; else d1[n * 128 + (t >> 1)] = sg;
}

// ---------------- fused fmix + NHWC bf16 pack ----------------
__global__ __launch_bounds__(256) void k_fmixT(const float* __restrict__ low, const float* __restrict__ high,
                                               const float* __restrict__ ssl, const float* __restrict__ ssh,
                                               const float* __restrict__ d0, const float* __restrict__ d1,
                                               unsigned short* __restrict__ outT) {
  __shared__ float ld[64 * 129];
  int t = threadIdx.x;
  int h = blockIdx.x, n = blockIdx.y;
  const long long sb = (long long)n * 128 * HW + h * 128;
  unsigned short* dst = outT + (long long)n * NHWC_N + ((long long)(h + 1) * 130 + 1) * 128;
  for (int half = 0; half < 2; ++half) {
    __syncthreads();
    for (int e = t; e < 8192; e += 256) {
      int c = e >> 7, w = e & 127;
      int cg = half * 64 + c;
      float xl = fmaxf(fmaf(low[sb + (long long)cg * HW + w], ssl[cg], ssl[128 + cg]), 0.f);
      float xh = fmaxf(fmaf(high[sb + (long long)cg * HW + w], ssh[cg], ssh[128 + cg]), 0.f);
      ld[c * 129 + w] = d0[n * 128 + cg] * xl + d1[n * 128 + cg] * xh;
    }
    __syncthreads();
    for (int q = t; q < 1024; q += 256) {
      int w = q >> 3, cg8 = q & 7;
      bf16x8 pk;
      #pragma unroll
      for (int u = 0; u < 8; ++u) pk[u] = (short)f2b(ld[(cg8 * 8 + u) * 129 + w]);
      *(bf16x8*)(dst + (long long)w * 128 + half * 64 + cg8 * 8) = pk;
    }
  }
}

static void make_taps(int ks, double sigma, Taps* tp) {
  double c = (ks - 1) / 2.0, sum = 0.0, v[7];
  for (int i = 0; i < ks; ++i) { double d = i - c; v[i] = std::exp(-d * d / (2.0 * sigma * sigma)); sum += v[i]; }
  for (int i = 0; i < 7; ++i) tp->g[i] = (i < ks) ? (float)(v[i] / sum) : 0.f;
}

extern "C" void kernel_launch(void* const* d_in, const int* in_sizes, int n_in,
                              void* d_out, int out_size, void* d_ws, size_t ws_size,
                              hipStream_t stream) {
  const float* x         = (const float*)d_in[0];
  const float* dwconv_w  = (const float*)d_in[1];
  const float* dwconv_b  = (const float*)d_in[2];
  const float* qkvl_w    = (const float*)d_in[3];
  const float* qkvl_b    = (const float*)d_in[4];
  const float* reproj_w  = (const float*)d_in[5];
  const float* reproj_b  = (const float*)d_in[6];
  const float* queries_w = (const float*)d_in[7];
  const float* queries_b = (const float*)d_in[8];
  const float* sff_low_w = (const float*)d_in[9];
  const float* sff_low_g = (const float*)d_in[10];
  const float* sff_low_b = (const float*)d_in[11];
  const float* sff_high_w= (const float*)d_in[12];
  const float* sff_high_g= (const float*)d_in[13];
  const float* sff_high_b= (const float*)d_in[14];
  const float* sff_c1_w  = (const float*)d_in[15];
  const float* sff_c2_w  = (const float*)d_in[16];
  const float* out_conv_w= (const float*)d_in[17];
  const float* out_bn_g  = (const float*)d_in[18];
  const float* out_bn_b  = (const float*)d_in[19];
  const float* out_proj_w= (const float*)d_in[20];
  const float* out_proj_b= (const float*)d_in[21];
  float* ws  = (float*)d_ws;
  float* out = (float*)d_out;

  float* x1   = ws + OFF_X1;
  float* qs   = ws + OFF_QS;
  float* kk   = ws + OFF_KK;
  float* x2o  = ws + OFF_X2O;
  float* vv   = ws + OFF_V;
  float* lf   = ws + OFF_LF;
  float* qp   = ws + OFF_QP;
  float* kp   = ws + OFF_KP;
  float* ctx  = ws + U;
  float* attp = ws;
  float* qx   = ws;
  float* lowc = ws;
  float* highc= ws + U;
  float* ybuf = ws;             // B1 (lowc dead after fmixT)
  float* qkb  = ws + OFF_QKB;
  float* Abuf = ws + OFF_AA;
  float* Mq   = ws + OFF_MQ;
  float* Dq   = ws + OFF_DQ;
  float* pm   = ws + OFF_PMAX;
  float* psv  = ws + OFF_PSUM;
  float* Mc   = ws + OFF_MC;
  float* Dc   = ws + OFF_DC;
  float* att  = ws + OFF_ATT;
  float* ssl  = ws + OFF_SSL;
  float* ssh  = ws + OFF_SSH;
  float* ssy  = ws + OFF_SSY;
  float* dv   = ws + OFF_DV;
  float* d0v  = ws + OFF_D0;
  float* d1v  = ws + OFF_D1;
  unsigned short* wqk   = (unsigned short*)(ws + OFF_WQK);
  unsigned short* wlow  = (unsigned short*)(ws + OFF_WLOW);
  unsigned short* whigh = (unsigned short*)(ws + OFF_WHIGH);
  unsigned short* wout  = (unsigned short*)(ws + OFF_WOUT);
  unsigned short* effT  = (unsigned short*)out;      // d_out NHWC bf16 (front 34.6MB)
  unsigned short* freqT = (unsigned short*)(ws + U); // B2 front
  unsigned short* fT    = (unsigned short*)out;      // reuses effT region (halo already zero)
  float* ctxp  = out + DOFF_CTXP;                    // d_out tail scratch
  float* partA = out + DOFF_PARTA;
  float* partB = out + DOFF_PARTB;

  Taps t3, t5, t7;
  const double s3 = std::pow(2.0, 1.0 / 3.0);
  make_taps(3, 1.6, &t3);
  make_taps(5, 1.6 * s3, &t5);
  make_taps(7, 1.6 * s3 * s3, &t7);

  dim3 b256(256), b128(128);

  // ---- phase 1: eff -> effT ----
  k_wpackq<<<dim3(40), b256, 0, stream>>>(qkvl_w, wqk);
  k_haloz<<<dim3(258), b256, 0, stream>>>(effT);
  k_dwconv<<<dim3(32768), b256, 0, stream>>>(x, dwconv_w, dwconv_b, x1);
  k_qkvlm<<<dim3(256, 8), b256, 0, stream>>>(x, wqk, qkvl_b, qs, kk, vv, lf);
  k_avgpool<<<dim3(4096), b256, 0, stream>>>(qs, qp);
  k_maxpool<<<dim3(4096), b256, 0, stream>>>(kk, kp);
  k_qk<<<dim3(32, 8), b256, 0, stream>>>(qp, kp, qkb);
  k_qksm<<<dim3(8), dim3(32), 0, stream>>>(qkb, Abuf);
  k_x2o<<<dim3(512), b256, 0, stream>>>(Abuf, vv, x2o);
  k_gemm1x1m<M_EFF><<<dim3(128, 8), b256, 0, stream>>>(reproj_w, x1, lf, x2o, reproj_b,
                                                       nullptr, nullptr, nullptr, nullptr, effT);
  // ---- phase 2: ctx / att ----
  k_blur3<<<dim3(4, 1024), b256, 0, stream>>>(x, ctx, ctxp, t3, t5, t7);
  k_ctx_red<<<dim3(4), b256, 0, stream>>>(ctxp, Mc, Dc);
  k_attm<<<dim3(32, 8), b256, 0, stream>>>(ctx, Mc, Dc, attp);
  k_attred<<<dim3(512), b256, 0, stream>>>(attp, att);
  // ---- phase 3: qx -> freqT ----
  k_gemm1x1m<M_QX><<<dim3(128, 8), b256, 0, stream>>>(queries_w, x, nullptr, nullptr, queries_b,
                                                      nullptr, nullptr, nullptr, nullptr, qx);
  k_qx_stat1<<<dim3(128, 8), b128, 0, stream>>>(qx, pm, psv);
  k_qx_stat2<<<dim3(8), b128, 0, stream>>>(pm, psv, Mq, Dq);
  k_wpack<<<dim3(576), b256, 0, stream>>>(sff_low_w, wlow);
  k_wpack<<<dim3(576), b256, 0, stream>>>(sff_high_w, whigh);
  k_wpack<<<dim3(576), b256, 0, stream>>>(out_conv_w, wout);
  k_haloz<<<dim3(258), b256, 0, stream>>>(freqT);
  k_gemm1x1m<M_FREQ><<<dim3(128, 8), b256, 0, stream>>>(att, qx, nullptr, nullptr, nullptr,
                                                        nullptr, Mq, Dq, x, freqT);
  // ---- phase 4: convs (+fused BN partials) / power / mix / out ----
  k_conv3l<<<dim3(128, 8), b256, 0, stream>>>(freqT, wlow, lowc, partA);
  k_conv3l<<<dim3(128, 8), b256, 0, stream>>>(effT, whigh, highc, partB);
  k_bnred<<<dim3(128), b256, 0, stream>>>(partA, sff_low_g, sff_low_b, ssl);
  k_bnred<<<dim3(128), b256, 0, stream>>>(partB, sff_high_g, sff_high_b, ssh);
  k_power<<<dim3(128, 8), b256, 0, stream>>>(lowc, ssl, dv, 0);
  k_power<<<dim3(128, 8), b256, 0, stream>>>(highc, ssh, dv, 1);
  k_dvec<<<dim3(8), b256, 0, stream>>>(dv, sff_c1_w, sff_c2_w, d0v, d1v);
  k_fmixT<<<dim3(128, 8), b256, 0, stream>>>(lowc, highc, ssl, ssh, d0v, d1v, fT);
  k_conv3l<<<dim3(128, 8), b256, 0, stream>>>(fT, wout, ybuf, partA);
  k_bnred<<<dim3(128), b256, 0, stream>>>(partA, out_bn_g, out_bn_b, ssy);
  k_gemm1x1m<M_OUT><<<dim3(128, 8), b256, 0, stream>>>(out_proj_w, ybuf, nullptr, nullptr, out_proj_b,
                                                       ssy, nullptr, nullptr, nullptr, out);
  (void)in_sizes; (void)n_in; (void)out_size; (void)ws_size;
}

// Round 23
// 1029.845 us; speedup vs baseline: 1.0429x; 1.0429x over previous
//
#include <hip/hip_runtime.h>
#include <hip/hip_bf16.h>
#include <cmath>

#define DEVFN __device__ __forceinline__

constexpr int HW = 16384;                      // 128*128
constexpr long long U = 16777216LL;            // 8*128*16384 floats
constexpr long long NHWC_N = 2163200LL;        // 130*130*128 ushorts per image

typedef __attribute__((ext_vector_type(8))) short bf16x8;
typedef __attribute__((ext_vector_type(4))) float f32x4;
typedef __attribute__((ext_vector_type(4))) unsigned short u16x4;

// ---- workspace layout (floats). B1 = ws[0,U), B2 = ws[U,2U), S = ws[2U,...). ~130 MB. ----
constexpr long long OFF_X1   = 0;
constexpr long long OFF_QS   = U/2;
constexpr long long OFF_KK   = 3*U/4;
constexpr long long OFF_X2O  = U/2;
constexpr long long OFF_V    = U;
constexpr long long OFF_LF   = U + U/4;
constexpr long long OFF_QP   = U + U/2;
constexpr long long OFF_KP   = U + U/2 + 1048576;
constexpr long long S0       = 2*U;
constexpr long long OFF_QKB  = S0;
constexpr long long OFF_AA   = S0 + 8192;
constexpr long long OFF_MQ   = S0 + 16384;
constexpr long long OFF_DQ   = S0 + 17408;
constexpr long long OFF_PMAX = S0 + 18432;     // 131072 (later: bf16 weight packs)
constexpr long long OFF_PSUM = S0 + 149504;    // 131072
constexpr long long OFF_MC   = S0 + 280576;
constexpr long long OFF_DC   = S0 + 281600;
constexpr long long OFF_ATT  = S0 + 282624;    // 131072
constexpr long long OFF_SSL  = S0 + 430080;
constexpr long long OFF_SSH  = S0 + 430336;
constexpr long long OFF_SSY  = S0 + 430592;
constexpr long long OFF_DV   = S0 + 430848;
constexpr long long OFF_D0   = S0 + 432896;
constexpr long long OFF_D1   = S0 + 433920;
constexpr long long OFF_WQK  = S0 + 434944;    // 5120 floats
constexpr long long OFF_WLOW  = OFF_PMAX;
constexpr long long OFF_WHIGH = OFF_PMAX + 73728;
constexpr long long OFF_WOUT  = OFF_PMAX + 147456;
// scratch in d_out tail (floats; NHWC region ends at float 8,652,800)
constexpr long long DOFF_CTXP  = 9000000;      // 8192 floats
constexpr long long DOFF_PARTA = 9100000;      // 131072 floats (512 blocks x 128 co x 2)
constexpr long long DOFF_PARTB = 9700000;      // 131072

struct Taps { float g[7]; };

DEVFN float gelu_f(float v) { return 0.5f * v * (1.0f + erff(v * 0.7071067811865475f)); }
DEVFN unsigned short f2b(float f) {
  unsigned u = __float_as_uint(f);
  unsigned r = u + 0x7fffu + ((u >> 16) & 1u);
  return (unsigned short)(r >> 16);
}
DEVFN unsigned pk2(float a, float b) {
  return (unsigned)f2b(a) | ((unsigned)f2b(b) << 16);
}

// ---------------- depthwise 3x3 + gelu on even channels ----------------
__global__ __launch_bounds__(256) void k_dwconv(const float* __restrict__ x, const float* __restrict__ w9,
                                                const float* __restrict__ bia, float* __restrict__ out) {
  int g = blockIdx.x * 256 + threadIdx.x;
  int w = g & 127, h = (g >> 7) & 127, c = (g >> 14) & 63, n = g >> 20;
  const float* src = x + (long long)(n * 128 + 2 * c) * HW;
  float acc = bia[c];
  #pragma unroll
  for (int ky = 0; ky < 3; ++ky) {
    int h2 = h + ky - 1;
    if ((unsigned)h2 < 128u) {
      #pragma unroll
      for (int kx = 0; kx < 3; ++kx) {
        int w2 = w + kx - 1;
        if ((unsigned)w2 < 128u) acc = fmaf(w9[c * 9 + ky * 3 + kx], src[h2 * 128 + w2], acc);
      }
    }
  }
  out[(long long)(n * 64 + c) * HW + h * 128 + w] = gelu_f(acc);
}

// ---------------- pack qkvl weights ----------------
__global__ __launch_bounds__(256) void k_wpackq(const float* __restrict__ w, unsigned short* __restrict__ wp) {
  int g = blockIdx.x * 256 + threadIdx.x;
  if (g < 10240) wp[g] = f2b(w[g]);
}

// ---------------- qkvl 1x1 conv (64->160) via bf16 MFMA, 64-px tiles for occupancy ----------------
__global__ __launch_bounds__(256) void k_qkvlm(const float* __restrict__ x, const unsigned short* __restrict__ wqk,
                                               const float* __restrict__ bq, float* __restrict__ qs,
                                               float* __restrict__ kk, float* __restrict__ vv,
                                               float* __restrict__ lf) {
  __shared__ unsigned int Bs[64 * 36];         // 9216 B; reused as [32][68] f32 in epilogue
  const int t = threadIdx.x;
  const int bx = blockIdx.x, n = blockIdx.y;   // bx in [0,256)
  const int pxb = bx * 64;
  #pragma unroll
  for (int it = 0; it < 8; ++it) {
    int e = it * 256 + t;
    int px = e & 63, k2 = e >> 6;
    float v0 = x[(long long)(n * 128 + 4 * k2 + 1) * HW + pxb + px];
    float v1 = x[(long long)(n * 128 + 4 * k2 + 3) * HW + pxb + px];
    Bs[px * 36 + k2] = pk2(v0, v1);
  }
  __syncthreads();
  const int wid = t >> 6, lane = t & 63, l15 = lane & 15, l4 = lane >> 4;
  f32x4 acc[10];
  #pragma unroll
  for (int m = 0; m < 10; ++m) { f32x4 z = {0.f,0.f,0.f,0.f}; acc[m] = z; }
  #pragma unroll
  for (int ks = 0; ks < 2; ++ks) {
    bf16x8 bfr = *(const bf16x8*)(&Bs[(wid * 16 + l15) * 36 + ks * 16 + l4 * 4]);
    #pragma unroll
    for (int mf = 0; mf < 10; ++mf) {
      bf16x8 af = *(const bf16x8*)(wqk + (mf * 16 + l15) * 64 + ks * 32 + l4 * 8);
      acc[mf] = __builtin_amdgcn_mfma_f32_16x16x32_bf16(af, bfr, acc[mf], 0, 0, 0);
    }
  }
  float* sT = (float*)Bs;                      // [32][68]
  const int pxl = wid * 16 + l15;
  const int jo = t >> 3, p0 = (t & 7) * 8;
  #pragma unroll
  for (int tau = 0; tau < 4; ++tau) {
    __syncthreads();
    #pragma unroll
    for (int mf = 0; mf < 2; ++mf) {
      #pragma unroll
      for (int r = 0; r < 4; ++r) {
        int j = mf * 16 + l4 * 4 + r;
        float v;
        if (tau == 0)
          v = gelu_f(acc[mf][r] + bq[j]) + gelu_f(acc[mf + 2][r] + bq[32 + j]);
        else
          v = gelu_f(acc[2 + 2 * tau + mf][r] + bq[32 * (tau + 1) + j]);
        sT[j * 68 + pxl] = v;
      }
    }
    __syncthreads();
    float* dstp = (tau == 0) ? qs : (tau == 1) ? kk : (tau == 2) ? vv : lf;
    long long o = (long long)(n * 32 + jo) * HW + pxb + p0;
    #pragma unroll
    for (int q4 = 0; q4 < 2; ++q4)
      *(f32x4*)&dstp[o + q4 * 4] = *(const f32x4*)&sT[jo * 68 + p0 + q4 * 4];
  }
}

// ---------------- pools ----------------
__global__ __launch_bounds__(256) void k_avgpool(const float* __restrict__ in, float* __restrict__ out) {
  int g = blockIdx.x * 256 + threadIdx.x;
  int ow = g & 63, oh = (g >> 6) & 63, c = (g >> 12) & 31, n = g >> 17;
  const float* src = in + (long long)(n * 32 + c) * HW;
  float s = 0.f;
  #pragma unroll
  for (int i = 0; i < 3; ++i) {
    int h = oh * 2 - 1 + i;
    if ((unsigned)h < 128u) {
      #pragma unroll
      for (int j = 0; j < 3; ++j) {
        int w = ow * 2 - 1 + j;
        if ((unsigned)w < 128u) s += src[h * 128 + w];
      }
    }
  }
  out[(long long)(n * 32 + c) * 4096 + oh * 64 + ow] = s * (1.f / 9.f);
}

__global__ __launch_bounds__(256) void k_maxpool(const float* __restrict__ in, float* __restrict__ out) {
  int g = blockIdx.x * 256 + threadIdx.x;
  int ow = g & 63, oh = (g >> 6) & 63, c = (g >> 12) & 31, n = g >> 17;
  const float* src = in + (long long)(n * 32 + c) * HW;
  float m = -3.0e38f;
  #pragma unroll
  for (int i = 0; i < 2; ++i)
    #pragma unroll
    for (int j = 0; j < 2; ++j)
      m = fmaxf(m, src[(oh * 2 + i) * 128 + ow * 2 + j]);
  out[(long long)(n * 32 + c) * 4096 + oh * 64 + ow] = m;
}

// ---------------- qk (32x32 per n, K=4096) ----------------
__global__ __launch_bounds__(256) void k_qk(const float* __restrict__ qp, const float* __restrict__ kp,
                                            float* __restrict__ qk) {
  int c = blockIdx.x, n = blockIdx.y;
  int t = threadIdx.x, d = t >> 3, r = t & 7;
  const float* qr = qp + (long long)(n * 32 + c) * 4096;
  const float* kr = kp + (long long)(n * 32 + d) * 4096;
  float acc = 0.f;
  for (int p = r; p < 4096; p += 8) acc = fmaf(qr[p], kr[p], acc);
  acc += __shfl_down(acc, 4, 8);
  acc += __shfl_down(acc, 2, 8);
  acc += __shfl_down(acc, 1, 8);
  if (r == 0) qk[(n * 32 + c) * 32 + d] = acc;
}

__global__ void k_qksm(const float* __restrict__ qk, float* __restrict__ A) {
  int n = blockIdx.x, d = threadIdx.x;
  float m = -3.0e38f;
  for (int c = 0; c < 32; ++c) m = fmaxf(m, qk[(n * 32 + c) * 32 + d]);
  float s = 0.f;
  for (int c = 0; c < 32; ++c) s += expf(qk[(n * 32 + c) * 32 + d] - m);
  float inv = 1.f / s;
  for (int c = 0; c < 32; ++c) A[(n * 32 + c) * 32 + d] = expf(qk[(n * 32 + c) * 32 + d] - m) * inv;
}

// ---------------- x2o = A^T @ v ----------------
__global__ __launch_bounds__(256) void k_x2o(const float* __restrict__ A, const float* __restrict__ vsrc,
                                             float* __restrict__ out) {
  __shared__ float lA[1024];
  int t = threadIdx.x;
  int g = blockIdx.x * 256 + t;
  int n = g >> 14, p = g & 16383;
  for (int e = t; e < 1024; e += 256) lA[e] = A[n * 1024 + e];
  __syncthreads();
  float acc[32];
  #pragma unroll
  for (int i = 0; i < 32; ++i) acc[i] = 0.f;
  for (int q = 0; q < 32; ++q) {
    float vv = vsrc[(long long)(n * 32 + q) * HW + p];
    #pragma unroll
    for (int k2 = 0; k2 < 32; ++k2) acc[k2] = fmaf(lA[q * 32 + k2], vv, acc[k2]);
  }
  #pragma unroll
  for (int k2 = 0; k2 < 32; ++k2) out[(long long)(n * 32 + k2) * HW + p] = acc[k2];
}

// ---------------- 128x128x128 GEMMs via bf16 MFMA ----------------
enum { M_EFF = 0, M_QX = 1, M_OUT = 2, M_FREQ = 3 };

template <int MODE>
__global__ __launch_bounds__(256) void k_gemm1x1m(
    const float* __restrict__ Amat, const float* __restrict__ B0, const float* __restrict__ B1,
    const float* __restrict__ B2, const float* __restrict__ bias, const float* __restrict__ scale,
    const float* __restrict__ Mq, const float* __restrict__ invDq, const float* __restrict__ xres,
    void* __restrict__ outp) {
  __shared__ unsigned int As[128 * 36];
  __shared__ unsigned int Bs[128 * 36];
  const int t = threadIdx.x;
  const int bx = blockIdx.x, n = blockIdx.y;
  const int pxb = bx * 128;
  const int wid = t >> 6, lane = t & 63, l15 = lane & 15, l4 = lane >> 4;
  const int wy = wid >> 1, wx = wid & 1;
  f32x4 acc[4][4];
  #pragma unroll
  for (int i = 0; i < 4; ++i)
    #pragma unroll
    for (int j = 0; j < 4; ++j) { f32x4 z = {0.f,0.f,0.f,0.f}; acc[i][j] = z; }

  for (int kc = 0; kc < 2; ++kc) {
    __syncthreads();
    if (MODE == M_FREQ) {
      #pragma unroll
      for (int it = 0; it < 16; ++it) {
        int e = it * 256 + t;
        int i = e & 127, j2l = e >> 7;
        int j = kc * 64 + 2 * j2l;
        float v0 = Amat[(long long)(n * 128 + j) * 128 + i];
        float v1 = Amat[(long long)(n * 128 + j + 1) * 128 + i];
        As[i * 36 + j2l] = pk2(v0, v1);
      }
    } else {
      #pragma unroll
      for (int it = 0; it < 16; ++it) {
        int e = it * 256 + t;
        int m = e >> 5, k2l = e & 31;
        float2 v = *(const float2*)(&Amat[m * 128 + kc * 64 + 2 * k2l]);
        As[m * 36 + k2l] = pk2(v.x, v.y);
      }
    }
    if (MODE == M_FREQ) {
      #pragma unroll
      for (int it = 0; it < 16; ++it) {
        int e = it * 256 + t;
        int j2l = e & 31, px = e >> 5;
        int j = kc * 64 + 2 * j2l;
        long long qb = ((long long)n * HW + pxb + px) * 128 + j;
        float2 v = *(const float2*)(&B0[qb]);
        float e0 = expf(v.x - Mq[n * 128 + j]) * invDq[n * 128 + j];
        float e1 = expf(v.y - Mq[n * 128 + j + 1]) * invDq[n * 128 + j + 1];
        Bs[px * 36 + j2l] = pk2(e0, e1);
      }
    } else {
      #pragma unroll
      for (int it = 0; it < 16; ++it) {
        int e = it * 256 + t;
        int px = e & 127, k2l = e >> 7;
        int ci = kc * 64 + 2 * k2l;
        float v0, v1;
        if (MODE == M_EFF) {
          if (ci < 64) {
            v0 = B0[(long long)(n * 64 + ci) * HW + pxb + px];
            v1 = B0[(long long)(n * 64 + ci + 1) * HW + pxb + px];
          } else if (ci < 96) {
            v0 = B1[(long long)(n * 32 + ci - 64) * HW + pxb + px];
            v1 = B1[(long long)(n * 32 + ci - 63) * HW + pxb + px];
          } else {
            v0 = B2[(long long)(n * 32 + ci - 96) * HW + pxb + px];
            v1 = B2[(long long)(n * 32 + ci - 95) * HW + pxb + px];
          }
        } else if (MODE == M_QX) {
          v0 = B0[(long long)(n * 128 + ci) * HW + pxb + px];
          v1 = B0[(long long)(n * 128 + ci + 1) * HW + pxb + px];
        } else {
          float u0 = B0[(long long)(n * 128 + ci) * HW + pxb + px];
          float u1 = B0[(long long)(n * 128 + ci + 1) * HW + pxb + px];
          v0 = fmaxf(fmaf(u0, scale[ci], scale[128 + ci]), 0.f);
          v1 = fmaxf(fmaf(u1, scale[ci + 1], scale[128 + ci + 1]), 0.f);
        }
        Bs[px * 36 + k2l] = pk2(v0, v1);
      }
    }
    __syncthreads();
    #pragma unroll
    for (int ks = 0; ks < 2; ++ks) {
      bf16x8 af[4], bfr[4];
      #pragma unroll
      for (int mf = 0; mf < 4; ++mf)
        af[mf] = *(const bf16x8*)(&As[(wy * 64 + mf * 16 + l15) * 36 + ks * 16 + l4 * 4]);
      #pragma unroll
      for (int nf = 0; nf < 4; ++nf)
        bfr[nf] = *(const bf16x8*)(&Bs[(wx * 64 + nf * 16 + l15) * 36 + ks * 16 + l4 * 4]);
      #pragma unroll
      for (int mf = 0; mf < 4; ++mf)
        #pragma unroll
        for (int nf = 0; nf < 4; ++nf)
          acc[mf][nf] = __builtin_amdgcn_mfma_f32_16x16x32_bf16(af[mf], bfr[nf], acc[mf][nf], 0, 0, 0);
    }
  }
  if (MODE == M_EFF || MODE == M_FREQ) {
    unsigned short* oT = (unsigned short*)outp;
    #pragma unroll
    for (int nf = 0; nf < 4; ++nf) {
      int px = pxb + wx * 64 + nf * 16 + l15;
      int hh = px >> 7, wwp = (px & 127) + 1;
      long long rb = (long long)n * NHWC_N + ((long long)(hh + 1) * 130 + wwp) * 128;
      #pragma unroll
      for (int mf = 0; mf < 4; ++mf) {
        int ch = wy * 64 + mf * 16 + l4 * 4;
        u16x4 pk;
        #pragma unroll
        for (int r = 0; r < 4; ++r) {
          float v = acc[mf][nf][r] + ((MODE == M_EFF) ? bias[ch + r] : 0.f);
          if (MODE == M_FREQ) v += xres[(long long)(n * 128 + ch + r) * HW + px];
          pk[r] = f2b(v);
        }
        *(u16x4*)(&oT[rb + ch]) = pk;
      }
    }
  } else {
    float* of = (float*)outp;
    #pragma unroll
    for (int mf = 0; mf < 4; ++mf)
      #pragma unroll
      for (int nf = 0; nf < 4; ++nf) {
        int px = pxb + wx * 64 + nf * 16 + l15;
        #pragma unroll
        for (int r = 0; r < 4; ++r) {
          int ch = wy * 64 + mf * 16 + l4 * 4 + r;
          of[(long long)(n * 128 + ch) * HW + px] = acc[mf][nf][r] + bias[ch];
        }
      }
  }
}

// ---------------- qx softmax stats (fused max+sum, then cross-c reduce) ----------------
__global__ __launch_bounds__(128) void k_qx_stat1(const float* __restrict__ qx, float* __restrict__ pm,
                                                  float* __restrict__ ps) {
  int c = blockIdx.x, n = blockIdx.y, w = threadIdx.x;
  long long base = (long long)(n * 128 + c) * HW + w;
  float m = -3.0e38f;
  for (int h = 0; h < 128; ++h) m = fmaxf(m, qx[base + h * 128]);
  float s = 0.f;
  for (int h = 0; h < 128; ++h) s += expf(qx[base + h * 128] - m);
  pm[(n * 128 + c) * 128 + w] = m;
  ps[(n * 128 + c) * 128 + w] = s;
}
__global__ __launch_bounds__(128) void k_qx_stat2(const float* __restrict__ pm, const float* __restrict__ ps,
                                                  float* __restrict__ Mq, float* __restrict__ Dq) {
  int n = blockIdx.x, w = threadIdx.x;
  float M = -3.0e38f;
  for (int c = 0; c < 128; ++c) M = fmaxf(M, pm[(n * 128 + c) * 128 + w]);
  float D = 0.f;
  for (int c = 0; c < 128; ++c) D += ps[(n * 128 + c) * 128 + w] * expf(pm[(n * 128 + c) * 128 + w] - M);
  Mq[n * 128 + w] = M;
  Dq[n * 128 + w] = 1.f / D;
}

// ---------------- fused 3-stage gaussian pyramid + ctx + online softmax partials ----------------
constexpr int BROWS = 44;
constexpr int BSTR  = 144;

template <int R, int HLO, int HHI, int VLO, int VHI>
DEVFN void blur_stage4(float* sA, float* sB, const float* __restrict__ g, int h0, int t) {
  __syncthreads();
  constexpr int HN = (HHI - HLO + 1) * 32;
  for (int e = t; e < HN; e += 256) {
    int r = HLO + (e >> 5), g4 = e & 31;
    int base = r * BSTR + 8 + g4 * 4;
    f32x4 a = *(const f32x4*)&sA[base - 4];
    f32x4 b = *(const f32x4*)&sA[base];
    f32x4 c = *(const f32x4*)&sA[base + 4];
    float m[12] = {a[0], a[1], a[2], a[3], b[0], b[1], b[2], b[3], c[0], c[1], c[2], c[3]};
    f32x4 s;
    #pragma unroll
    for (int j = 0; j < 4; ++j) {
      float acc = 0.f;
      #pragma unroll
      for (int d = -R; d <= R; ++d) acc = fmaf(g[d + R], m[4 + j + d], acc);
      s[j] = acc;
    }
    *(f32x4*)&sB[base] = s;
  }
  __syncthreads();
  constexpr int VN = (VHI - VLO + 1) * 32;
  for (int e = t; e < VN; e += 256) {
    int r = VLO + (e >> 5), g4 = e & 31;
    int base = r * BSTR + 8 + g4 * 4;
    f32x4 s = {0.f, 0.f, 0.f, 0.f};
    #pragma unroll
    for (int d = -R; d <= R; ++d) {
      f32x4 v = *(const f32x4*)&sB[base + d * BSTR];
      #pragma unroll
      for (int j = 0; j < 4; ++j) s[j] = fmaf(g[d + R], v[j], s[j]);
    }
    int h = h0 - 6 + r;
    if ((unsigned)h >= 128u) { f32x4 z = {0.f, 0.f, 0.f, 0.f}; s = z; }
    *(f32x4*)&sA[base] = s;
  }
}

__global__ __launch_bounds__(256) void k_blur3(const float* __restrict__ x, float* __restrict__ ctx,
                                               float* __restrict__ ctxp, Taps t3, Taps t5, Taps t7) {
  __shared__ float sA[BROWS * BSTR];
  __shared__ float sB[BROWS * BSTR];
  __shared__ float rm[256], rs[256];
  const int t = threadIdx.x;
  const int ht = blockIdx.x, h0 = ht * 32;
  const long long nc = blockIdx.y;
  const float* src = x + nc * HW;
  for (int e = t; e < BROWS * BSTR; e += 256) {
    int r = e / BSTR, wp = e % BSTR;
    int w = wp - 8, h = h0 - 6 + r;
    sA[e] = ((unsigned)h < 128u && (unsigned)w < 128u) ? src[h * 128 + w] : 0.f;
  }
  blur_stage4<1, 0, 43, 1, 42>(sA, sB, t3.g, h0, t);
  blur_stage4<2, 1, 42, 3, 40>(sA, sB, t5.g, h0, t);
  blur_stage4<3, 3, 40, 6, 37>(sA, sB, t7.g, h0, t);
  __syncthreads();
  long long ob = nc * HW + (long long)h0 * 128;
  float lm = -3.0e38f, lsum = 0.f;
  for (int e = t; e < 1024; e += 256) {
    int r = e >> 5, g4 = e & 31;
    f32x4 xs = *(const f32x4*)&src[(h0 + r) * 128 + g4 * 4];
    f32x4 bl = *(const f32x4*)&sA[(6 + r) * BSTR + 8 + g4 * 4];
    f32x4 v;
    #pragma unroll
    for (int j = 0; j < 4; ++j) {
      v[j] = xs[j] - bl[j];
      float val = v[j];
      if (val > lm) { lsum = lsum * expf(lm - val) + 1.f; lm = val; }
      else lsum += expf(val - lm);
    }
    *(f32x4*)&ctx[ob + r * 128 + g4 * 4] = v;
  }
  rm[t] = lm; rs[t] = lsum; __syncthreads();
  for (int o = 128; o > 0; o >>= 1) {
    if (t < o) {
      float m2 = rm[t + o], s2 = rs[t + o];
      float M = fmaxf(rm[t], m2);
      rs[t] = rs[t] * expf(rm[t] - M) + s2 * expf(m2 - M);
      rm[t] = M;
    }
    __syncthreads();
  }
  if (t == 0) { ctxp[nc * 8 + ht * 2] = rm[0]; ctxp[nc * 8 + ht * 2 + 1] = rs[0]; }
}

__global__ __launch_bounds__(256) void k_ctx_red(const float* __restrict__ ctxp, float* __restrict__ Mc,
                                                 float* __restrict__ Dc) {
  int g = blockIdx.x * 256 + threadIdx.x;   // 1024
  float M = -3.0e38f, S = 0.f;
  #pragma unroll
  for (int i = 0; i < 4; ++i) {
    float m2 = ctxp[g * 8 + i * 2], s2 = ctxp[g * 8 + i * 2 + 1];
    float Mn = fmaxf(M, m2);
    S = S * expf(M - Mn) + s2 * expf(m2 - Mn);
    M = Mn;
  }
  Mc[g] = M; Dc[g] = 1.f / S;
}

// ---------------- att = softmax(ctx) @ ctx^T via bf16 MFMA (partials) ----------------
__global__ __launch_bounds__(256) void k_attm(const float* __restrict__ ctx, const float* __restrict__ Mc,
                                              const float* __restrict__ invDc, float* __restrict__ attp) {
  __shared__ unsigned int As[128 * 36];
  __shared__ unsigned int Bs[128 * 36];
  const int t = threadIdx.x, sp = blockIdx.x, n = blockIdx.y;
  const int wid = t >> 6, lane = t & 63, l15 = lane & 15, l4 = lane >> 4;
  const int wy = wid >> 1, wx = wid & 1;
  f32x4 acc[4][4];
  #pragma unroll
  for (int i = 0; i < 4; ++i)
    #pragma unroll
    for (int j = 0; j < 4; ++j) { f32x4 z = {0.f,0.f,0.f,0.f}; acc[i][j] = z; }
  for (int kc = 0; kc < 8; ++kc) {
    __syncthreads();
    int pb = sp * 512 + kc * 64;
    #pragma unroll
    for (int it = 0; it < 16; ++it) {
      int e = it * 256 + t;
      int row = e >> 5, p2 = e & 31;
      float2 v = *(const float2*)(&ctx[(long long)(n * 128 + row) * HW + pb + 2 * p2]);
      float m = Mc[n * 128 + row], d = invDc[n * 128 + row];
      Bs[row * 36 + p2] = pk2(v.x, v.y);
      As[row * 36 + p2] = pk2(expf(v.x - m) * d, expf(v.y - m) * d);
    }
    __syncthreads();
    #pragma unroll
    for (int ks = 0; ks < 2; ++ks) {
      bf16x8 af[4], bfr[4];
      #pragma unroll
      for (int mf = 0; mf < 4; ++mf)
        af[mf] = *(const bf16x8*)(&As[(wy * 64 + mf * 16 + l15) * 36 + ks * 16 + l4 * 4]);
      #pragma unroll
      for (int nf = 0; nf < 4; ++nf)
        bfr[nf] = *(const bf16x8*)(&Bs[(wx * 64 + nf * 16 + l15) * 36 + ks * 16 + l4 * 4]);
      #pragma unroll
      for (int mf = 0; mf < 4; ++mf)
        #pragma unroll
        for (int nf = 0; nf < 4; ++nf)
          acc[mf][nf] = __builtin_amdgcn_mfma_f32_16x16x32_bf16(af[mf], bfr[nf], acc[mf][nf], 0, 0, 0);
    }
  }
  long long ob = (long long)(sp * 8 + n) * 16384;
  #pragma unroll
  for (int mf = 0; mf < 4; ++mf)
    #pragma unroll
    for (int nf = 0; nf < 4; ++nf) {
      int d = wx * 64 + nf * 16 + l15;
      #pragma unroll
      for (int r = 0; r < 4; ++r) {
        int c = wy * 64 + mf * 16 + l4 * 4 + r;
        attp[ob + c * 128 + d] = acc[mf][nf][r];
      }
    }
}

__global__ __launch_bounds__(256) void k_attred(const float* __restrict__ attp, float* __restrict__ att) {
  int g = blockIdx.x * 256 + threadIdx.x;
  float s = 0.f;
  for (int sp = 0; sp < 32; ++sp) s += attp[(long long)sp * 131072 + g];
  att[g] = s;
}

// ---------------- pack conv weight -> bf16 [co][tap*128+ci] ----------------
__global__ __launch_bounds__(256) void k_wpack(const float* __restrict__ w, unsigned short* __restrict__ wp) {
  int g = blockIdx.x * 256 + threadIdx.x;
  int ci = g & 127;
  int tap = (g >> 7) % 9;
  int co = g / 1152;
  wp[g] = f2b(w[co * 1152 + ci * 9 + tap]);
}

// ---------------- zero halo of padded NHWC bf16 ----------------
__global__ __launch_bounds__(256) void k_haloz(unsigned short* __restrict__ p) {
  int idx = blockIdx.x * 256 + threadIdx.x;
  if (idx >= 66048) return;
  int n = idx / 8256;
  int r = idx % 8256;
  int cell = r >> 4, q = r & 15;
  int h, w;
  if (cell < 130)      { h = 0;   w = cell; }
  else if (cell < 260) { h = 129; w = cell - 130; }
  else if (cell < 388) { h = cell - 260 + 1; w = 0; }
  else                 { h = cell - 388 + 1; w = 129; }
  uint4 z = {0u, 0u, 0u, 0u};
  *(uint4*)(p + (long long)n * NHWC_N + ((long long)h * 130 + w) * 128 + q * 8) = z;
}

// ---------------- 3x3 conv: 2-row x 128-px tiles, bf16 MFMA, gload_lds dbuf, slot-swizzled LDS ----------------
// LDS per kc-chunk: [row 4][w 130][ch 32] bf16 = 33280 B, double-buffered (66560 B).
// Slot swizzle: LDS slot s of column w holds global 8-ch slot s ^ ((w>>1)&3) -> 2-way (free) ds_read_b128.
__global__ __launch_bounds__(256) void k_conv3l(const unsigned short* __restrict__ inT,
                                                const unsigned short* __restrict__ wp,
                                                float* __restrict__ out,
                                                float* __restrict__ part) {
  __shared__ unsigned short Bs[2 * 16640];     // 66560 B
  const int t = threadIdx.x;
  const int bx = blockIdx.x, n = blockIdx.y;   // bx in [0,64)
  const int h0 = bx * 2;
  const int wid = t >> 6, lane = t & 63;
  const int wy = wid >> 1, wx = wid & 1;
  const int l15 = lane & 15, l4 = lane >> 4;
  f32x4 acc[4][4][2];
  #pragma unroll
  for (int i = 0; i < 4; ++i)
    #pragma unroll
    for (int j = 0; j < 4; ++j)
      #pragma unroll
      for (int ro = 0; ro < 2; ++ro) { f32x4 z = {0.f, 0.f, 0.f, 0.f}; acc[i][j][ro] = z; }
  const unsigned short* abase = wp + (wy * 64 + l15) * 1152 + l4 * 8;

  // stage one kc-chunk (2080 16B-chunks: 4 rows x 130 w x 4 slots) into Bs[buf], source-swizzled
  auto STAGE = [&](int kc, int buf) {
    const unsigned short* gb = inT + (long long)n * NHWC_N + kc * 32;
    #pragma unroll
    for (int it = 0; it < 9; ++it) {
      int cbase = it * 256 + wid * 64;
      int c = cbase + lane;
      if (c < 2080) {
        int row = c / 520, rem = c % 520;
        int w = rem >> 2, slot = rem & 3;
        int sg = slot ^ ((w >> 1) & 3);
        const unsigned short* src = gb + ((long long)(h0 + row) * 130 + w) * 128 + sg * 8;
        __builtin_amdgcn_global_load_lds(
            (const __attribute__((address_space(1))) unsigned int*)src,
            (__attribute__((address_space(3))) unsigned int*)&Bs[buf * 16640 + cbase * 8],
            16, 0, 0);
      }
    }
  };

  STAGE(0, 0);
  #pragma unroll
  for (int kc = 0; kc < 4; ++kc) {
    __syncthreads();
    if (kc < 3) STAGE(kc + 1, (kc + 1) & 1);
    const int lb = (kc & 1) * 16640;
    #pragma unroll
    for (int ky = 0; ky < 3; ++ky) {
      #pragma unroll
      for (int kx = 0; kx < 3; ++kx) {
        const int tap = ky * 3 + kx;
        bf16x8 af[4], bfr[4][2];
        #pragma unroll
        for (int cf = 0; cf < 4; ++cf)
          af[cf] = *(const bf16x8*)(abase + cf * 16 * 1152 + tap * 128 + kc * 32);
        #pragma unroll
        for (int pf = 0; pf < 4; ++pf) {
          int w = wx * 64 + pf * 16 + l15 + kx;
          int sr = l4 ^ ((w >> 1) & 3);
          #pragma unroll
          for (int ro = 0; ro < 2; ++ro)
            bfr[pf][ro] = *(const bf16x8*)(&Bs[lb + (ro + ky) * 4160 + w * 32 + sr * 8]);
        }
        #pragma unroll
        for (int cf = 0; cf < 4; ++cf)
          #pragma unroll
          for (int pf = 0; pf < 4; ++pf)
            #pragma unroll
            for (int ro = 0; ro < 2; ++ro)
              acc[cf][pf][ro] = __builtin_amdgcn_mfma_f32_16x16x32_bf16(af[cf], bfr[pf][ro], acc[cf][pf][ro], 0, 0, 0);
      }
    }
  }
  #pragma unroll
  for (int ro = 0; ro < 2; ++ro) {
    long long ob = (long long)n * 128 * HW + (h0 + ro) * 128;
    #pragma unroll
    for (int cf = 0; cf < 4; ++cf)
      #pragma unroll
      for (int pf = 0; pf < 4; ++pf) {
        int co = wy * 64 + cf * 16 + l4 * 4;
        int w  = wx * 64 + pf * 16 + l15;
        #pragma unroll
        for (int r = 0; r < 4; ++r)
          out[ob + (long long)(co + r) * HW + w] = acc[cf][pf][ro][r];
      }
  }
  // BN partials: per-co sum / sumsq over this block's 256 px (2 rows x 128 w)
  __shared__ float redS[4][64], redQ[4][64];
  #pragma unroll
  for (int cf = 0; cf < 4; ++cf)
    #pragma unroll
    for (int r = 0; r < 4; ++r) {
      float s = 0.f, q = 0.f;
      #pragma unroll
      for (int pf = 0; pf < 4; ++pf)
        #pragma unroll
        for (int ro = 0; ro < 2; ++ro) { float v = acc[cf][pf][ro][r]; s += v; q = fmaf(v, v, q); }
      #pragma unroll
      for (int off = 1; off < 16; off <<= 1) { s += __shfl_xor(s, off, 16); q += __shfl_xor(q, off, 16); }
      if (l15 == 0) { redS[wid][cf * 16 + l4 * 4 + r] = s; redQ[wid][cf * 16 + l4 * 4 + r] = q; }
    }
  __syncthreads();
  if (t < 128) {
    int wy2 = t >> 6, col = t & 63;
    int co = wy2 * 64 + col;
    float s = redS[wy2 * 2][col] + redS[wy2 * 2 + 1][col];
    float q = redQ[wy2 * 2][col] + redQ[wy2 * 2 + 1][col];
    long long pb = ((long long)(n * 64 + bx) * 128 + co) * 2;
    part[pb] = s; part[pb + 1] = q;
  }
}

// ---------------- BN reduce over 512 block-partials ----------------
__global__ __launch_bounds__(256) void k_bnred(const float* __restrict__ part, const float* __restrict__ g,
                                               const float* __restrict__ bb, float* __restrict__ ssout) {
  int c = blockIdx.x, t = threadIdx.x;
  float s = 0.f, q = 0.f;
  for (int b = t; b < 512; b += 256) {
    s += part[((long long)b * 128 + c) * 2];
    q += part[((long long)b * 128 + c) * 2 + 1];
  }
  __shared__ float r1[256], r2[256];
  r1[t] = s; r2[t] = q; __syncthreads();
  for (int o = 128; o > 0; o >>= 1) { if (t < o) { r1[t] += r1[t + o]; r2[t] += r2[t + o]; } __syncthreads(); }
  if (t == 0) {
    float mean = r1[0] / 131072.f;
    float var = r2[0] / 131072.f - mean * mean;
    float sc = g[c] * rsqrtf(var + 1e-5f);
    ssout[c] = sc;
    ssout[128 + c] = bb[c] - mean * sc;
  }
}

// ---------------- cubic power-mean per (n,c) ----------------
__global__ __launch_bounds__(256) void k_power(const float* __restrict__ in, const float* __restrict__ ss,
                                               float* __restrict__ dst, int off) {
  int c = blockIdx.x, n = blockIdx.y, t = threadIdx.x;
  float sc = ss[c], sh = ss[128 + c];
  long long base = (long long)(n * 128 + c) * HW;
  float s = 0.f;
  for (int i = t; i < HW; i += 256) {
    float r = fmaxf(fmaf(in[base + i], sc, sh), 0.f);
    s += r * r * r;
  }
  __shared__ float red[256];
  red[t] = s; __syncthreads();
  for (int o = 128; o > 0; o >>= 1) { if (t < o) red[t] += red[t + o]; __syncthreads(); }
  if (t == 0) dst[n * 256 + 2 * c + off] = cbrtf(red[0] * (1.f / 16384.f) + 1e-12f);
}

// ---------------- 1d conv x2 + sigmoid ----------------
__global__ __launch_bounds__(256) void k_dvec(const float* __restrict__ din, const float* __restrict__ c1,
                                              const float* __restrict__ c2, float* __restrict__ d0,
                                              float* __restrict__ d1) {
  __shared__ float a[256], b[256];
  int n = blockIdx.x, t = threadIdx.x;
  a[t] = din[n * 256 + t];
  __syncthreads();
  float acc = 0.f;
  #pragma unroll
  for (int k = 0; k < 5; ++k) { int j = t + k - 2; if (0 <= j && j < 256) acc = fmaf(c1[k], a[j], acc); }
  b[t] = acc; __syncthreads();
  float acc2 = 0.f;
  #pragma unroll
  for (int k = 0; k < 5; ++k) { int j = t + k - 2; if (0 <= j && j < 256) acc2 = fmaf(c2[k], b[j], acc2); }
  float sg = 1.f / (1.f + expf(-acc2));
  if ((t & 1) == 0) d0[n * 128 + (t >> 1)] = sg; else d1[n * 128 + (t >> 1)] = sg;
}

// ---------------- fused fmix + NHWC bf16 pack ----------------
__global__ __launch_bounds__(256) void k_fmixT(const float* __restrict__ low, const float* __restrict__ high,
                                               const float* __restrict__ ssl, const float* __restrict__ ssh,
                                               const float* __restrict__ d0, const float* __restrict__ d1,
                                               unsigned short* __restrict__ outT) {
  __shared__ float ld[64 * 129];
  int t = threadIdx.x;
  int h = blockIdx.x, n = blockIdx.y;
  const long long sb = (long long)n * 128 * HW + h * 128;
  unsigned short* dst = outT + (long long)n * NHWC_N + ((long long)(h + 1) * 130 + 1) * 128;
  for (int half = 0; half < 2; ++half) {
    __syncthreads();
    for (int e = t; e < 8192; e += 256) {
      int c = e >> 7, w = e & 127;
      int cg = half * 64 + c;
      float xl = fmaxf(fmaf(low[sb + (long long)cg * HW + w], ssl[cg], ssl[128 + cg]), 0.f);
      float xh = fmaxf(fmaf(high[sb + (long long)cg * HW + w], ssh[cg], ssh[128 + cg]), 0.f);
      ld[c * 129 + w] = d0[n * 128 + cg] * xl + d1[n * 128 + cg] * xh;
    }
    __syncthreads();
    for (int q = t; q < 1024; q += 256) {
      int w = q >> 3, cg8 = q & 7;
      bf16x8 pk;
      #pragma unroll
      for (int u = 0; u < 8; ++u) pk[u] = (short)f2b(ld[(cg8 * 8 + u) * 129 + w]);
      *(bf16x8*)(dst + (long long)w * 128 + half * 64 + cg8 * 8) = pk;
    }
  }
}

static void make_taps(int ks, double sigma, Taps* tp) {
  double c = (ks - 1) / 2.0, sum = 0.0, v[7];
  for (int i = 0; i < ks; ++i) { double d = i - c; v[i] = std::exp(-d * d / (2.0 * sigma * sigma)); sum += v[i]; }
  for (int i = 0; i < 7; ++i) tp->g[i] = (i < ks) ? (float)(v[i] / sum) : 0.f;
}

extern "C" void kernel_launch(void* const* d_in, const int* in_sizes, int n_in,
                              void* d_out, int out_size, void* d_ws, size_t ws_size,
                              hipStream_t stream) {
  const float* x         = (const float*)d_in[0];
  const float* dwconv_w  = (const float*)d_in[1];
  const float* dwconv_b  = (const float*)d_in[2];
  const float* qkvl_w    = (const float*)d_in[3];
  const float* qkvl_b    = (const float*)d_in[4];
  const float* reproj_w  = (const float*)d_in[5];
  const float* reproj_b  = (const float*)d_in[6];
  const float* queries_w = (const float*)d_in[7];
  const float* queries_b = (const float*)d_in[8];
  const float* sff_low_w = (const float*)d_in[9];
  const float* sff_low_g = (const float*)d_in[10];
  const float* sff_low_b = (const float*)d_in[11];
  const float* sff_high_w= (const float*)d_in[12];
  const float* sff_high_g= (const float*)d_in[13];
  const float* sff_high_b= (const float*)d_in[14];
  const float* sff_c1_w  = (const float*)d_in[15];
  const float* sff_c2_w  = (const float*)d_in[16];
  const float* out_conv_w= (const float*)d_in[17];
  const float* out_bn_g  = (const float*)d_in[18];
  const float* out_bn_b  = (const float*)d_in[19];
  const float* out_proj_w= (const float*)d_in[20];
  const float* out_proj_b= (const float*)d_in[21];
  float* ws  = (float*)d_ws;
  float* out = (float*)d_out;

  float* x1   = ws + OFF_X1;
  float* qs   = ws + OFF_QS;
  float* kk   = ws + OFF_KK;
  float* x2o  = ws + OFF_X2O;
  float* vv   = ws + OFF_V;
  float* lf   = ws + OFF_LF;
  float* qp   = ws + OFF_QP;
  float* kp   = ws + OFF_KP;
  float* ctx  = ws + U;
  float* attp = ws;
  float* qx   = ws;
  float* lowc = ws;
  float* highc= ws + U;
  float* ybuf = ws;             // B1 (lowc dead after fmixT)
  float* qkb  = ws + OFF_QKB;
  float* Abuf = ws + OFF_AA;
  float* Mq   = ws + OFF_MQ;
  float* Dq   = ws + OFF_DQ;
  float* pm   = ws + OFF_PMAX;
  float* psv  = ws + OFF_PSUM;
  float* Mc   = ws + OFF_MC;
  float* Dc   = ws + OFF_DC;
  float* att  = ws + OFF_ATT;
  float* ssl  = ws + OFF_SSL;
  float* ssh  = ws + OFF_SSH;
  float* ssy  = ws + OFF_SSY;
  float* dv   = ws + OFF_DV;
  float* d0v  = ws + OFF_D0;
  float* d1v  = ws + OFF_D1;
  unsigned short* wqk   = (unsigned short*)(ws + OFF_WQK);
  unsigned short* wlow  = (unsigned short*)(ws + OFF_WLOW);
  unsigned short* whigh = (unsigned short*)(ws + OFF_WHIGH);
  unsigned short* wout  = (unsigned short*)(ws + OFF_WOUT);
  unsigned short* effT  = (unsigned short*)out;      // d_out NHWC bf16 (front 34.6MB)
  unsigned short* freqT = (unsigned short*)(ws + U); // B2 front
  unsigned short* fT    = (unsigned short*)out;      // reuses effT region (halo already zero)
  float* ctxp  = out + DOFF_CTXP;                    // d_out tail scratch
  float* partA = out + DOFF_PARTA;
  float* partB = out + DOFF_PARTB;

  Taps t3, t5, t7;
  const double s3 = std::pow(2.0, 1.0 / 3.0);
  make_taps(3, 1.6, &t3);
  make_taps(5, 1.6 * s3, &t5);
  make_taps(7, 1.6 * s3 * s3, &t7);

  dim3 b256(256), b128(128);

  // ---- phase 1: eff -> effT ----
  k_wpackq<<<dim3(40), b256, 0, stream>>>(qkvl_w, wqk);
  k_haloz<<<dim3(258), b256, 0, stream>>>(effT);
  k_dwconv<<<dim3(32768), b256, 0, stream>>>(x, dwconv_w, dwconv_b, x1);
  k_qkvlm<<<dim3(256, 8), b256, 0, stream>>>(x, wqk, qkvl_b, qs, kk, vv, lf);
  k_avgpool<<<dim3(4096), b256, 0, stream>>>(qs, qp);
  k_maxpool<<<dim3(4096), b256, 0, stream>>>(kk, kp);
  k_qk<<<dim3(32, 8), b256, 0, stream>>>(qp, kp, qkb);
  k_qksm<<<dim3(8), dim3(32), 0, stream>>>(qkb, Abuf);
  k_x2o<<<dim3(512), b256, 0, stream>>>(Abuf, vv, x2o);
  k_gemm1x1m<M_EFF><<<dim3(128, 8), b256, 0, stream>>>(reproj_w, x1, lf, x2o, reproj_b,
                                                       nullptr, nullptr, nullptr, nullptr, effT);
  // ---- phase 2: ctx / att ----
  k_blur3<<<dim3(4, 1024), b256, 0, stream>>>(x, ctx, ctxp, t3, t5, t7);
  k_ctx_red<<<dim3(4), b256, 0, stream>>>(ctxp, Mc, Dc);
  k_attm<<<dim3(32, 8), b256, 0, stream>>>(ctx, Mc, Dc, attp);
  k_attred<<<dim3(512), b256, 0, stream>>>(attp, att);
  // ---- phase 3: qx -> freqT ----
  k_gemm1x1m<M_QX><<<dim3(128, 8), b256, 0, stream>>>(queries_w, x, nullptr, nullptr, queries_b,
                                                      nullptr, nullptr, nullptr, nullptr, qx);
  k_qx_stat1<<<dim3(128, 8), b128, 0, stream>>>(qx, pm, psv);
  k_qx_stat2<<<dim3(8), b128, 0, stream>>>(pm, psv, Mq, Dq);
  k_wpack<<<dim3(576), b256, 0, stream>>>(sff_low_w, wlow);
  k_wpack<<<dim3(576), b256, 0, stream>>>(sff_high_w, whigh);
  k_wpack<<<dim3(576), b256, 0, stream>>>(out_conv_w, wout);
  k_haloz<<<dim3(258), b256, 0, stream>>>(freqT);
  k_gemm1x1m<M_FREQ><<<dim3(128, 8), b256, 0, stream>>>(att, qx, nullptr, nullptr, nullptr,
                                                        nullptr, Mq, Dq, x, freqT);
  // ---- phase 4: convs (+fused BN partials) / power / mix / out ----
  k_conv3l<<<dim3(64, 8), b256, 0, stream>>>(freqT, wlow, lowc, partA);
  k_conv3l<<<dim3(64, 8), b256, 0, stream>>>(effT, whigh, highc, partB);
  k_bnred<<<dim3(128), b256, 0, stream>>>(partA, sff_low_g, sff_low_b, ssl);
  k_bnred<<<dim3(128), b256, 0, stream>>>(partB, sff_high_g, sff_high_b, ssh);
  k_power<<<dim3(128, 8), b256, 0, stream>>>(lowc, ssl, dv, 0);
  k_power<<<dim3(128, 8), b256, 0, stream>>>(highc, ssh, dv, 1);
  k_dvec<<<dim3(8), b256, 0, stream>>>(dv, sff_c1_w, sff_c2_w, d0v, d1v);
  k_fmixT<<<dim3(128, 8), b256, 0, stream>>>(lowc, highc, ssl, ssh, d0v, d1v, fT);
  k_conv3l<<<dim3(64, 8), b256, 0, stream>>>(fT, wout, ybuf, partA);
  k_bnred<<<dim3(128), b256, 0, stream>>>(partA, out_bn_g, out_bn_b, ssy);
  k_gemm1x1m<M_OUT><<<dim3(128, 8), b256, 0, stream>>>(out_proj_w, ybuf, nullptr, nullptr, out_proj_b,
                                                       ssy, nullptr, nullptr, nullptr, out);
  (void)in_sizes; (void)n_in; (void)out_size; (void)ws_size;
}

// Round 24
// 1000.984 us; speedup vs baseline: 1.0730x; 1.0288x over previous
//
#include <hip/hip_runtime.h>
#include <hip/hip_bf16.h>
#include <cmath>

#define DEVFN __device__ __forceinline__

constexpr int HW = 16384;                      // 128*128
constexpr long long U = 16777216LL;            // 8*128*16384 floats
constexpr long long NHWC_N = 2163200LL;        // 130*130*128 ushorts per image

typedef __attribute__((ext_vector_type(8))) short bf16x8;
typedef __attribute__((ext_vector_type(4))) float f32x4;
typedef __attribute__((ext_vector_type(4))) unsigned short u16x4;

// ---- workspace layout (floats). B1 = ws[0,U), B2 = ws[U,2U), S = ws[2U,...). ~130 MB. ----
constexpr long long OFF_X1   = 0;
constexpr long long OFF_QS   = U/2;
constexpr long long OFF_KK   = 3*U/4;
constexpr long long OFF_X2O  = U/2;
constexpr long long OFF_V    = U;
constexpr long long OFF_LF   = U + U/4;
constexpr long long OFF_QP   = U + U/2;
constexpr long long OFF_KP   = U + U/2 + 1048576;
constexpr long long S0       = 2*U;
constexpr long long OFF_QKB  = S0;
constexpr long long OFF_AA   = S0 + 8192;
constexpr long long OFF_MQ   = S0 + 16384;
constexpr long long OFF_DQ   = S0 + 17408;
constexpr long long OFF_PMAX = S0 + 18432;     // 131072 (later: bf16 weight packs)
constexpr long long OFF_PSUM = S0 + 149504;    // 131072
constexpr long long OFF_MC   = S0 + 280576;
constexpr long long OFF_DC   = S0 + 281600;
constexpr long long OFF_ATT  = S0 + 282624;    // 131072
constexpr long long OFF_SSL  = S0 + 430080;
constexpr long long OFF_SSH  = S0 + 430336;
constexpr long long OFF_SSY  = S0 + 430592;
constexpr long long OFF_DV   = S0 + 430848;
constexpr long long OFF_D0   = S0 + 432896;
constexpr long long OFF_D1   = S0 + 433920;
constexpr long long OFF_WQK  = S0 + 434944;    // 5120 floats
constexpr long long OFF_WLOW  = OFF_PMAX;
constexpr long long OFF_WHIGH = OFF_PMAX + 73728;
constexpr long long OFF_WOUT  = OFF_PMAX + 147456;
// scratch in d_out tail (floats; NHWC region ends at float 8,652,800)
constexpr long long DOFF_CTXP  = 9000000;      // 8192 floats
constexpr long long DOFF_PARTA = 9100000;      // 131072 floats (512 blocks x 128 co x 2)
constexpr long long DOFF_PARTB = 9700000;      // 131072

struct Taps { float g[7]; };

DEVFN float gelu_f(float v) { return 0.5f * v * (1.0f + erff(v * 0.7071067811865475f)); }
DEVFN unsigned short f2b(float f) {
  unsigned u = __float_as_uint(f);
  unsigned r = u + 0x7fffu + ((u >> 16) & 1u);
  return (unsigned short)(r >> 16);
}
DEVFN unsigned pk2(float a, float b) {
  return (unsigned)f2b(a) | ((unsigned)f2b(b) << 16);
}

// ---------------- depthwise 3x3 + gelu on even channels ----------------
__global__ __launch_bounds__(256) void k_dwconv(const float* __restrict__ x, const float* __restrict__ w9,
                                                const float* __restrict__ bia, float* __restrict__ out) {
  int g = blockIdx.x * 256 + threadIdx.x;
  int w = g & 127, h = (g >> 7) & 127, c = (g >> 14) & 63, n = g >> 20;
  const float* src = x + (long long)(n * 128 + 2 * c) * HW;
  float acc = bia[c];
  #pragma unroll
  for (int ky = 0; ky < 3; ++ky) {
    int h2 = h + ky - 1;
    if ((unsigned)h2 < 128u) {
      #pragma unroll
      for (int kx = 0; kx < 3; ++kx) {
        int w2 = w + kx - 1;
        if ((unsigned)w2 < 128u) acc = fmaf(w9[c * 9 + ky * 3 + kx], src[h2 * 128 + w2], acc);
      }
    }
  }
  out[(long long)(n * 64 + c) * HW + h * 128 + w] = gelu_f(acc);
}

// ---------------- pack qkvl weights ----------------
__global__ __launch_bounds__(256) void k_wpackq(const float* __restrict__ w, unsigned short* __restrict__ wp) {
  int g = blockIdx.x * 256 + threadIdx.x;
  if (g < 10240) wp[g] = f2b(w[g]);
}

// ---------------- qkvl 1x1 conv (64->160) via bf16 MFMA, 64-px tiles for occupancy ----------------
__global__ __launch_bounds__(256) void k_qkvlm(const float* __restrict__ x, const unsigned short* __restrict__ wqk,
                                               const float* __restrict__ bq, float* __restrict__ qs,
                                               float* __restrict__ kk, float* __restrict__ vv,
                                               float* __restrict__ lf) {
  __shared__ unsigned int Bs[64 * 36];         // 9216 B; reused as [32][68] f32 in epilogue
  const int t = threadIdx.x;
  const int bx = blockIdx.x, n = blockIdx.y;   // bx in [0,256)
  const int pxb = bx * 64;
  #pragma unroll
  for (int it = 0; it < 8; ++it) {
    int e = it * 256 + t;
    int px = e & 63, k2 = e >> 6;
    float v0 = x[(long long)(n * 128 + 4 * k2 + 1) * HW + pxb + px];
    float v1 = x[(long long)(n * 128 + 4 * k2 + 3) * HW + pxb + px];
    Bs[px * 36 + k2] = pk2(v0, v1);
  }
  __syncthreads();
  const int wid = t >> 6, lane = t & 63, l15 = lane & 15, l4 = lane >> 4;
  f32x4 acc[10];
  #pragma unroll
  for (int m = 0; m < 10; ++m) { f32x4 z = {0.f,0.f,0.f,0.f}; acc[m] = z; }
  #pragma unroll
  for (int ks = 0; ks < 2; ++ks) {
    bf16x8 bfr = *(const bf16x8*)(&Bs[(wid * 16 + l15) * 36 + ks * 16 + l4 * 4]);
    #pragma unroll
    for (int mf = 0; mf < 10; ++mf) {
      bf16x8 af = *(const bf16x8*)(wqk + (mf * 16 + l15) * 64 + ks * 32 + l4 * 8);
      acc[mf] = __builtin_amdgcn_mfma_f32_16x16x32_bf16(af, bfr, acc[mf], 0, 0, 0);
    }
  }
  float* sT = (float*)Bs;                      // [32][68]
  const int pxl = wid * 16 + l15;
  const int jo = t >> 3, p0 = (t & 7) * 8;
  #pragma unroll
  for (int tau = 0; tau < 4; ++tau) {
    __syncthreads();
    #pragma unroll
    for (int mf = 0; mf < 2; ++mf) {
      #pragma unroll
      for (int r = 0; r < 4; ++r) {
        int j = mf * 16 + l4 * 4 + r;
        float v;
        if (tau == 0)
          v = gelu_f(acc[mf][r] + bq[j]) + gelu_f(acc[mf + 2][r] + bq[32 + j]);
        else
          v = gelu_f(acc[2 + 2 * tau + mf][r] + bq[32 * (tau + 1) + j]);
        sT[j * 68 + pxl] = v;
      }
    }
    __syncthreads();
    float* dstp = (tau == 0) ? qs : (tau == 1) ? kk : (tau == 2) ? vv : lf;
    long long o = (long long)(n * 32 + jo) * HW + pxb + p0;
    #pragma unroll
    for (int q4 = 0; q4 < 2; ++q4)
      *(f32x4*)&dstp[o + q4 * 4] = *(const f32x4*)&sT[jo * 68 + p0 + q4 * 4];
  }
}

// ---------------- pools (avg + max merged; blocks [0,4096) avg, [4096,8192) max) ----------------
__global__ __launch_bounds__(256) void k_pool(const float* __restrict__ qs, const float* __restrict__ kk,
                                              float* __restrict__ qp, float* __restrict__ kp) {
  if (blockIdx.x < 4096) {
    int g = blockIdx.x * 256 + threadIdx.x;
    int ow = g & 63, oh = (g >> 6) & 63, c = (g >> 12) & 31, n = g >> 17;
    const float* src = qs + (long long)(n * 32 + c) * HW;
    float s = 0.f;
    #pragma unroll
    for (int i = 0; i < 3; ++i) {
      int h = oh * 2 - 1 + i;
      if ((unsigned)h < 128u) {
        #pragma unroll
        for (int j = 0; j < 3; ++j) {
          int w = ow * 2 - 1 + j;
          if ((unsigned)w < 128u) s += src[h * 128 + w];
        }
      }
    }
    qp[(long long)(n * 32 + c) * 4096 + oh * 64 + ow] = s * (1.f / 9.f);
  } else {
    int g = (blockIdx.x - 4096) * 256 + threadIdx.x;
    int ow = g & 63, oh = (g >> 6) & 63, c = (g >> 12) & 31, n = g >> 17;
    const float* src = kk + (long long)(n * 32 + c) * HW;
    float m = -3.0e38f;
    #pragma unroll
    for (int i = 0; i < 2; ++i)
      #pragma unroll
      for (int j = 0; j < 2; ++j)
        m = fmaxf(m, src[(oh * 2 + i) * 128 + ow * 2 + j]);
    kp[(long long)(n * 32 + c) * 4096 + oh * 64 + ow] = m;
  }
}

// ---------------- qk (32x32 per n, K=4096) ----------------
__global__ __launch_bounds__(256) void k_qk(const float* __restrict__ qp, const float* __restrict__ kp,
                                            float* __restrict__ qk) {
  int c = blockIdx.x, n = blockIdx.y;
  int t = threadIdx.x, d = t >> 3, r = t & 7;
  const float* qr = qp + (long long)(n * 32 + c) * 4096;
  const float* kr = kp + (long long)(n * 32 + d) * 4096;
  float acc = 0.f;
  for (int p = r; p < 4096; p += 8) acc = fmaf(qr[p], kr[p], acc);
  acc += __shfl_down(acc, 4, 8);
  acc += __shfl_down(acc, 2, 8);
  acc += __shfl_down(acc, 1, 8);
  if (r == 0) qk[(n * 32 + c) * 32 + d] = acc;
}

__global__ void k_qksm(const float* __restrict__ qk, float* __restrict__ A) {
  int n = blockIdx.x, d = threadIdx.x;
  float m = -3.0e38f;
  for (int c = 0; c < 32; ++c) m = fmaxf(m, qk[(n * 32 + c) * 32 + d]);
  float s = 0.f;
  for (int c = 0; c < 32; ++c) s += expf(qk[(n * 32 + c) * 32 + d] - m);
  float inv = 1.f / s;
  for (int c = 0; c < 32; ++c) A[(n * 32 + c) * 32 + d] = expf(qk[(n * 32 + c) * 32 + d] - m) * inv;
}

// ---------------- x2o = A^T @ v ----------------
__global__ __launch_bounds__(256) void k_x2o(const float* __restrict__ A, const float* __restrict__ vsrc,
                                             float* __restrict__ out) {
  __shared__ float lA[1024];
  int t = threadIdx.x;
  int g = blockIdx.x * 256 + t;
  int n = g >> 14, p = g & 16383;
  for (int e = t; e < 1024; e += 256) lA[e] = A[n * 1024 + e];
  __syncthreads();
  float acc[32];
  #pragma unroll
  for (int i = 0; i < 32; ++i) acc[i] = 0.f;
  for (int q = 0; q < 32; ++q) {
    float vv = vsrc[(long long)(n * 32 + q) * HW + p];
    #pragma unroll
    for (int k2 = 0; k2 < 32; ++k2) acc[k2] = fmaf(lA[q * 32 + k2], vv, acc[k2]);
  }
  #pragma unroll
  for (int k2 = 0; k2 < 32; ++k2) out[(long long)(n * 32 + k2) * HW + p] = acc[k2];
}

// ---------------- 128x128x128 GEMMs via bf16 MFMA ----------------
enum { M_EFF = 0, M_QX = 1, M_OUT = 2, M_FREQ = 3 };

template <int MODE>
__global__ __launch_bounds__(256) void k_gemm1x1m(
    const float* __restrict__ Amat, const float* __restrict__ B0, const float* __restrict__ B1,
    const float* __restrict__ B2, const float* __restrict__ bias, const float* __restrict__ scale,
    const float* __restrict__ Mq, const float* __restrict__ invDq, const float* __restrict__ xres,
    void* __restrict__ outp) {
  __shared__ unsigned int As[128 * 36];
  __shared__ unsigned int Bs[128 * 36];
  const int t = threadIdx.x;
  const int bx = blockIdx.x, n = blockIdx.y;
  const int pxb = bx * 128;
  const int wid = t >> 6, lane = t & 63, l15 = lane & 15, l4 = lane >> 4;
  const int wy = wid >> 1, wx = wid & 1;
  f32x4 acc[4][4];
  #pragma unroll
  for (int i = 0; i < 4; ++i)
    #pragma unroll
    for (int j = 0; j < 4; ++j) { f32x4 z = {0.f,0.f,0.f,0.f}; acc[i][j] = z; }

  for (int kc = 0; kc < 2; ++kc) {
    __syncthreads();
    if (MODE == M_FREQ) {
      #pragma unroll
      for (int it = 0; it < 16; ++it) {
        int e = it * 256 + t;
        int i = e & 127, j2l = e >> 7;
        int j = kc * 64 + 2 * j2l;
        float v0 = Amat[(long long)(n * 128 + j) * 128 + i];
        float v1 = Amat[(long long)(n * 128 + j + 1) * 128 + i];
        As[i * 36 + j2l] = pk2(v0, v1);
      }
    } else {
      #pragma unroll
      for (int it = 0; it < 16; ++it) {
        int e = it * 256 + t;
        int m = e >> 5, k2l = e & 31;
        float2 v = *(const float2*)(&Amat[m * 128 + kc * 64 + 2 * k2l]);
        As[m * 36 + k2l] = pk2(v.x, v.y);
      }
    }
    if (MODE == M_FREQ) {
      #pragma unroll
      for (int it = 0; it < 16; ++it) {
        int e = it * 256 + t;
        int j2l = e & 31, px = e >> 5;
        int j = kc * 64 + 2 * j2l;
        long long qb = ((long long)n * HW + pxb + px) * 128 + j;
        float2 v = *(const float2*)(&B0[qb]);
        float e0 = expf(v.x - Mq[n * 128 + j]) * invDq[n * 128 + j];
        float e1 = expf(v.y - Mq[n * 128 + j + 1]) * invDq[n * 128 + j + 1];
        Bs[px * 36 + j2l] = pk2(e0, e1);
      }
    } else {
      #pragma unroll
      for (int it = 0; it < 16; ++it) {
        int e = it * 256 + t;
        int px = e & 127, k2l = e >> 7;
        int ci = kc * 64 + 2 * k2l;
        float v0, v1;
        if (MODE == M_EFF) {
          if (ci < 64) {
            v0 = B0[(long long)(n * 64 + ci) * HW + pxb + px];
            v1 = B0[(long long)(n * 64 + ci + 1) * HW + pxb + px];
          } else if (ci < 96) {
            v0 = B1[(long long)(n * 32 + ci - 64) * HW + pxb + px];
            v1 = B1[(long long)(n * 32 + ci - 63) * HW + pxb + px];
          } else {
            v0 = B2[(long long)(n * 32 + ci - 96) * HW + pxb + px];
            v1 = B2[(long long)(n * 32 + ci - 95) * HW + pxb + px];
          }
        } else if (MODE == M_QX) {
          v0 = B0[(long long)(n * 128 + ci) * HW + pxb + px];
          v1 = B0[(long long)(n * 128 + ci + 1) * HW + pxb + px];
        } else {
          float u0 = B0[(long long)(n * 128 + ci) * HW + pxb + px];
          float u1 = B0[(long long)(n * 128 + ci + 1) * HW + pxb + px];
          v0 = fmaxf(fmaf(u0, scale[ci], scale[128 + ci]), 0.f);
          v1 = fmaxf(fmaf(u1, scale[ci + 1], scale[128 + ci + 1]), 0.f);
        }
        Bs[px * 36 + k2l] = pk2(v0, v1);
      }
    }
    __syncthreads();
    #pragma unroll
    for (int ks = 0; ks < 2; ++ks) {
      bf16x8 af[4], bfr[4];
      #pragma unroll
      for (int mf = 0; mf < 4; ++mf)
        af[mf] = *(const bf16x8*)(&As[(wy * 64 + mf * 16 + l15) * 36 + ks * 16 + l4 * 4]);
      #pragma unroll
      for (int nf = 0; nf < 4; ++nf)
        bfr[nf] = *(const bf16x8*)(&Bs[(wx * 64 + nf * 16 + l15) * 36 + ks * 16 + l4 * 4]);
      #pragma unroll
      for (int mf = 0; mf < 4; ++mf)
        #pragma unroll
        for (int nf = 0; nf < 4; ++nf)
          acc[mf][nf] = __builtin_amdgcn_mfma_f32_16x16x32_bf16(af[mf], bfr[nf], acc[mf][nf], 0, 0, 0);
    }
  }
  if (MODE == M_EFF || MODE == M_FREQ) {
    unsigned short* oT = (unsigned short*)outp;
    #pragma unroll
    for (int nf = 0; nf < 4; ++nf) {
      int px = pxb + wx * 64 + nf * 16 + l15;
      int hh = px >> 7, wwp = (px & 127) + 1;
      long long rb = (long long)n * NHWC_N + ((long long)(hh + 1) * 130 + wwp) * 128;
      #pragma unroll
      for (int mf = 0; mf < 4; ++mf) {
        int ch = wy * 64 + mf * 16 + l4 * 4;
        u16x4 pk;
        #pragma unroll
        for (int r = 0; r < 4; ++r) {
          float v = acc[mf][nf][r] + ((MODE == M_EFF) ? bias[ch + r] : 0.f);
          if (MODE == M_FREQ) v += xres[(long long)(n * 128 + ch + r) * HW + px];
          pk[r] = f2b(v);
        }
        *(u16x4*)(&oT[rb + ch]) = pk;
      }
    }
  } else {
    float* of = (float*)outp;
    #pragma unroll
    for (int mf = 0; mf < 4; ++mf)
      #pragma unroll
      for (int nf = 0; nf < 4; ++nf) {
        int px = pxb + wx * 64 + nf * 16 + l15;
        #pragma unroll
        for (int r = 0; r < 4; ++r) {
          int ch = wy * 64 + mf * 16 + l4 * 4 + r;
          of[(long long)(n * 128 + ch) * HW + px] = acc[mf][nf][r] + bias[ch];
        }
      }
  }
}

// ---------------- qx softmax stats (fused max+sum, then cross-c reduce) ----------------
__global__ __launch_bounds__(128) void k_qx_stat1(const float* __restrict__ qx, float* __restrict__ pm,
                                                  float* __restrict__ ps) {
  int c = blockIdx.x, n = blockIdx.y, w = threadIdx.x;
  long long base = (long long)(n * 128 + c) * HW + w;
  float m = -3.0e38f;
  for (int h = 0; h < 128; ++h) m = fmaxf(m, qx[base + h * 128]);
  float s = 0.f;
  for (int h = 0; h < 128; ++h) s += expf(qx[base + h * 128] - m);
  pm[(n * 128 + c) * 128 + w] = m;
  ps[(n * 128 + c) * 128 + w] = s;
}
__global__ __launch_bounds__(128) void k_qx_stat2(const float* __restrict__ pm, const float* __restrict__ ps,
                                                  float* __restrict__ Mq, float* __restrict__ Dq) {
  int n = blockIdx.x, w = threadIdx.x;
  float M = -3.0e38f;
  for (int c = 0; c < 128; ++c) M = fmaxf(M, pm[(n * 128 + c) * 128 + w]);
  float D = 0.f;
  for (int c = 0; c < 128; ++c) D += ps[(n * 128 + c) * 128 + w] * expf(pm[(n * 128 + c) * 128 + w] - M);
  Mq[n * 128 + w] = M;
  Dq[n * 128 + w] = 1.f / D;
}

// ---------------- fused 3-stage gaussian pyramid + ctx + online softmax partials ----------------
constexpr int BROWS = 44;
constexpr int BSTR  = 144;

template <int R, int HLO, int HHI, int VLO, int VHI>
DEVFN void blur_stage4(float* sA, float* sB, const float* __restrict__ g, int h0, int t) {
  __syncthreads();
  constexpr int HN = (HHI - HLO + 1) * 32;
  for (int e = t; e < HN; e += 256) {
    int r = HLO + (e >> 5), g4 = e & 31;
    int base = r * BSTR + 8 + g4 * 4;
    f32x4 a = *(const f32x4*)&sA[base - 4];
    f32x4 b = *(const f32x4*)&sA[base];
    f32x4 c = *(const f32x4*)&sA[base + 4];
    float m[12] = {a[0], a[1], a[2], a[3], b[0], b[1], b[2], b[3], c[0], c[1], c[2], c[3]};
    f32x4 s;
    #pragma unroll
    for (int j = 0; j < 4; ++j) {
      float acc = 0.f;
      #pragma unroll
      for (int d = -R; d <= R; ++d) acc = fmaf(g[d + R], m[4 + j + d], acc);
      s[j] = acc;
    }
    *(f32x4*)&sB[base] = s;
  }
  __syncthreads();
  constexpr int VN = (VHI - VLO + 1) * 32;
  for (int e = t; e < VN; e += 256) {
    int r = VLO + (e >> 5), g4 = e & 31;
    int base = r * BSTR + 8 + g4 * 4;
    f32x4 s = {0.f, 0.f, 0.f, 0.f};
    #pragma unroll
    for (int d = -R; d <= R; ++d) {
      f32x4 v = *(const f32x4*)&sB[base + d * BSTR];
      #pragma unroll
      for (int j = 0; j < 4; ++j) s[j] = fmaf(g[d + R], v[j], s[j]);
    }
    int h = h0 - 6 + r;
    if ((unsigned)h >= 128u) { f32x4 z = {0.f, 0.f, 0.f, 0.f}; s = z; }
    *(f32x4*)&sA[base] = s;
  }
}

__global__ __launch_bounds__(256) void k_blur3(const float* __restrict__ x, float* __restrict__ ctx,
                                               float* __restrict__ ctxp, Taps t3, Taps t5, Taps t7) {
  __shared__ float sA[BROWS * BSTR];
  __shared__ float sB[BROWS * BSTR];
  __shared__ float rm[256], rs[256];
  const int t = threadIdx.x;
  const int ht = blockIdx.x, h0 = ht * 32;
  const long long nc = blockIdx.y;
  const float* src = x + nc * HW;
  for (int e = t; e < BROWS * BSTR; e += 256) {
    int r = e / BSTR, wp = e % BSTR;
    int w = wp - 8, h = h0 - 6 + r;
    sA[e] = ((unsigned)h < 128u && (unsigned)w < 128u) ? src[h * 128 + w] : 0.f;
  }
  blur_stage4<1, 0, 43, 1, 42>(sA, sB, t3.g, h0, t);
  blur_stage4<2, 1, 42, 3, 40>(sA, sB, t5.g, h0, t);
  blur_stage4<3, 3, 40, 6, 37>(sA, sB, t7.g, h0, t);
  __syncthreads();
  long long ob = nc * HW + (long long)h0 * 128;
  float lm = -3.0e38f, lsum = 0.f;
  for (int e = t; e < 1024; e += 256) {
    int r = e >> 5, g4 = e & 31;
    f32x4 xs = *(const f32x4*)&src[(h0 + r) * 128 + g4 * 4];
    f32x4 bl = *(const f32x4*)&sA[(6 + r) * BSTR + 8 + g4 * 4];
    f32x4 v;
    #pragma unroll
    for (int j = 0; j < 4; ++j) {
      v[j] = xs[j] - bl[j];
      float val = v[j];
      if (val > lm) { lsum = lsum * expf(lm - val) + 1.f; lm = val; }
      else lsum += expf(val - lm);
    }
    *(f32x4*)&ctx[ob + r * 128 + g4 * 4] = v;
  }
  rm[t] = lm; rs[t] = lsum; __syncthreads();
  for (int o = 128; o > 0; o >>= 1) {
    if (t < o) {
      float m2 = rm[t + o], s2 = rs[t + o];
      float M = fmaxf(rm[t], m2);
      rs[t] = rs[t] * expf(rm[t] - M) + s2 * expf(m2 - M);
      rm[t] = M;
    }
    __syncthreads();
  }
  if (t == 0) { ctxp[nc * 8 + ht * 2] = rm[0]; ctxp[nc * 8 + ht * 2 + 1] = rs[0]; }
}

__global__ __launch_bounds__(256) void k_ctx_red(const float* __restrict__ ctxp, float* __restrict__ Mc,
                                                 float* __restrict__ Dc) {
  int g = blockIdx.x * 256 + threadIdx.x;   // 1024
  float M = -3.0e38f, S = 0.f;
  #pragma unroll
  for (int i = 0; i < 4; ++i) {
    float m2 = ctxp[g * 8 + i * 2], s2 = ctxp[g * 8 + i * 2 + 1];
    float Mn = fmaxf(M, m2);
    S = S * expf(M - Mn) + s2 * expf(m2 - Mn);
    M = Mn;
  }
  Mc[g] = M; Dc[g] = 1.f / S;
}

// ---------------- att = softmax(ctx) @ ctx^T via bf16 MFMA (partials) ----------------
__global__ __launch_bounds__(256) void k_attm(const float* __restrict__ ctx, const float* __restrict__ Mc,
                                              const float* __restrict__ invDc, float* __restrict__ attp) {
  __shared__ unsigned int As[128 * 36];
  __shared__ unsigned int Bs[128 * 36];
  const int t = threadIdx.x, sp = blockIdx.x, n = blockIdx.y;
  const int wid = t >> 6, lane = t & 63, l15 = lane & 15, l4 = lane >> 4;
  const int wy = wid >> 1, wx = wid & 1;
  f32x4 acc[4][4];
  #pragma unroll
  for (int i = 0; i < 4; ++i)
    #pragma unroll
    for (int j = 0; j < 4; ++j) { f32x4 z = {0.f,0.f,0.f,0.f}; acc[i][j] = z; }
  for (int kc = 0; kc < 8; ++kc) {
    __syncthreads();
    int pb = sp * 512 + kc * 64;
    #pragma unroll
    for (int it = 0; it < 16; ++it) {
      int e = it * 256 + t;
      int row = e >> 5, p2 = e & 31;
      float2 v = *(const float2*)(&ctx[(long long)(n * 128 + row) * HW + pb + 2 * p2]);
      float m = Mc[n * 128 + row], d = invDc[n * 128 + row];
      Bs[row * 36 + p2] = pk2(v.x, v.y);
      As[row * 36 + p2] = pk2(expf(v.x - m) * d, expf(v.y - m) * d);
    }
    __syncthreads();
    #pragma unroll
    for (int ks = 0; ks < 2; ++ks) {
      bf16x8 af[4], bfr[4];
      #pragma unroll
      for (int mf = 0; mf < 4; ++mf)
        af[mf] = *(const bf16x8*)(&As[(wy * 64 + mf * 16 + l15) * 36 + ks * 16 + l4 * 4]);
      #pragma unroll
      for (int nf = 0; nf < 4; ++nf)
        bfr[nf] = *(const bf16x8*)(&Bs[(wx * 64 + nf * 16 + l15) * 36 + ks * 16 + l4 * 4]);
      #pragma unroll
      for (int mf = 0; mf < 4; ++mf)
        #pragma unroll
        for (int nf = 0; nf < 4; ++nf)
          acc[mf][nf] = __builtin_amdgcn_mfma_f32_16x16x32_bf16(af[mf], bfr[nf], acc[mf][nf], 0, 0, 0);
    }
  }
  long long ob = (long long)(sp * 8 + n) * 16384;
  #pragma unroll
  for (int mf = 0; mf < 4; ++mf)
    #pragma unroll
    for (int nf = 0; nf < 4; ++nf) {
      int d = wx * 64 + nf * 16 + l15;
      #pragma unroll
      for (int r = 0; r < 4; ++r) {
        int c = wy * 64 + mf * 16 + l4 * 4 + r;
        attp[ob + c * 128 + d] = acc[mf][nf][r];
      }
    }
}

__global__ __launch_bounds__(256) void k_attred(const float* __restrict__ attp, float* __restrict__ att) {
  int g = blockIdx.x * 256 + threadIdx.x;
  float s = 0.f;
  for (int sp = 0; sp < 32; ++sp) s += attp[(long long)sp * 131072 + g];
  att[g] = s;
}

// ---------------- pack conv weight -> bf16 [co][tap*128+ci]; blockIdx.y selects tensor ----------------
__global__ __launch_bounds__(256) void k_wpack(const float* __restrict__ w0, const float* __restrict__ w1,
                                               const float* __restrict__ w2, unsigned short* __restrict__ p0,
                                               unsigned short* __restrict__ p1, unsigned short* __restrict__ p2) {
  int y = blockIdx.y;
  const float* w = (y == 0) ? w0 : (y == 1) ? w1 : w2;
  unsigned short* wp = (y == 0) ? p0 : (y == 1) ? p1 : p2;
  int g = blockIdx.x * 256 + threadIdx.x;
  int ci = g & 127;
  int tap = (g >> 7) % 9;
  int co = g / 1152;
  wp[g] = f2b(w[co * 1152 + ci * 9 + tap]);
}

// ---------------- zero halo of padded NHWC bf16 ----------------
__global__ __launch_bounds__(256) void k_haloz(unsigned short* __restrict__ p) {
  int idx = blockIdx.x * 256 + threadIdx.x;
  if (idx >= 66048) return;
  int n = idx / 8256;
  int r = idx % 8256;
  int cell = r >> 4, q = r & 15;
  int h, w;
  if (cell < 130)      { h = 0;   w = cell; }
  else if (cell < 260) { h = 129; w = cell - 130; }
  else if (cell < 388) { h = cell - 260 + 1; w = 0; }
  else                 { h = cell - 388 + 1; w = 129; }
  uint4 z = {0u, 0u, 0u, 0u};
  *(uint4*)(p + (long long)n * NHWC_N + ((long long)h * 130 + w) * 128 + q * 8) = z;
}

// ---------------- 3x3 conv: 2-row x 128-px tiles, bf16 MFMA, gload_lds dbuf, slot-swizzled LDS ----------------
// blockIdx.z selects (input, weights, output, partials) pair -> two convs in one dispatch.
__global__ __launch_bounds__(256) void k_conv3l(const unsigned short* __restrict__ in0,
                                                const unsigned short* __restrict__ in1,
                                                const unsigned short* __restrict__ wp0,
                                                const unsigned short* __restrict__ wp1,
                                                float* __restrict__ out0, float* __restrict__ out1,
                                                float* __restrict__ part0, float* __restrict__ part1) {
  const int sel = blockIdx.z;
  const unsigned short* inT = sel ? in1 : in0;
  const unsigned short* wp  = sel ? wp1 : wp0;
  float* out  = sel ? out1 : out0;
  float* part = sel ? part1 : part0;
  __shared__ unsigned short Bs[2 * 16640];     // 66560 B
  const int t = threadIdx.x;
  const int bx = blockIdx.x, n = blockIdx.y;   // bx in [0,64)
  const int h0 = bx * 2;
  const int wid = t >> 6, lane = t & 63;
  const int wy = wid >> 1, wx = wid & 1;
  const int l15 = lane & 15, l4 = lane >> 4;
  f32x4 acc[4][4][2];
  #pragma unroll
  for (int i = 0; i < 4; ++i)
    #pragma unroll
    for (int j = 0; j < 4; ++j)
      #pragma unroll
      for (int ro = 0; ro < 2; ++ro) { f32x4 z = {0.f, 0.f, 0.f, 0.f}; acc[i][j][ro] = z; }
  const unsigned short* abase = wp + (wy * 64 + l15) * 1152 + l4 * 8;

  // stage one kc-chunk (2080 16B-chunks: 4 rows x 130 w x 4 slots) into Bs[buf], source-swizzled
  auto STAGE = [&](int kc, int buf) {
    const unsigned short* gb = inT + (long long)n * NHWC_N + kc * 32;
    #pragma unroll
    for (int it = 0; it < 9; ++it) {
      int cbase = it * 256 + wid * 64;
      int c = cbase + lane;
      if (c < 2080) {
        int row = c / 520, rem = c % 520;
        int w = rem >> 2, slot = rem & 3;
        int sg = slot ^ ((w >> 1) & 3);
        const unsigned short* src = gb + ((long long)(h0 + row) * 130 + w) * 128 + sg * 8;
        __builtin_amdgcn_global_load_lds(
            (const __attribute__((address_space(1))) unsigned int*)src,
            (__attribute__((address_space(3))) unsigned int*)&Bs[buf * 16640 + cbase * 8],
            16, 0, 0);
      }
    }
  };

  STAGE(0, 0);
  #pragma unroll
  for (int kc = 0; kc < 4; ++kc) {
    __syncthreads();
    if (kc < 3) STAGE(kc + 1, (kc + 1) & 1);
    const int lb = (kc & 1) * 16640;
    #pragma unroll
    for (int ky = 0; ky < 3; ++ky) {
      #pragma unroll
      for (int kx = 0; kx < 3; ++kx) {
        const int tap = ky * 3 + kx;
        bf16x8 af[4], bfr[4][2];
        #pragma unroll
        for (int cf = 0; cf < 4; ++cf)
          af[cf] = *(const bf16x8*)(abase + cf * 16 * 1152 + tap * 128 + kc * 32);
        #pragma unroll
        for (int pf = 0; pf < 4; ++pf) {
          int w = wx * 64 + pf * 16 + l15 + kx;
          int sr = l4 ^ ((w >> 1) & 3);
          #pragma unroll
          for (int ro = 0; ro < 2; ++ro)
            bfr[pf][ro] = *(const bf16x8*)(&Bs[lb + (ro + ky) * 4160 + w * 32 + sr * 8]);
        }
        #pragma unroll
        for (int cf = 0; cf < 4; ++cf)
          #pragma unroll
          for (int pf = 0; pf < 4; ++pf)
            #pragma unroll
            for (int ro = 0; ro < 2; ++ro)
              acc[cf][pf][ro] = __builtin_amdgcn_mfma_f32_16x16x32_bf16(af[cf], bfr[pf][ro], acc[cf][pf][ro], 0, 0, 0);
      }
    }
  }
  #pragma unroll
  for (int ro = 0; ro < 2; ++ro) {
    long long ob = (long long)n * 128 * HW + (h0 + ro) * 128;
    #pragma unroll
    for (int cf = 0; cf < 4; ++cf)
      #pragma unroll
      for (int pf = 0; pf < 4; ++pf) {
        int co = wy * 64 + cf * 16 + l4 * 4;
        int w  = wx * 64 + pf * 16 + l15;
        #pragma unroll
        for (int r = 0; r < 4; ++r)
          out[ob + (long long)(co + r) * HW + w] = acc[cf][pf][ro][r];
      }
  }
  // BN partials: per-co sum / sumsq over this block's 256 px (2 rows x 128 w)
  __shared__ float redS[4][64], redQ[4][64];
  #pragma unroll
  for (int cf = 0; cf < 4; ++cf)
    #pragma unroll
    for (int r = 0; r < 4; ++r) {
      float s = 0.f, q = 0.f;
      #pragma unroll
      for (int pf = 0; pf < 4; ++pf)
        #pragma unroll
        for (int ro = 0; ro < 2; ++ro) { float v = acc[cf][pf][ro][r]; s += v; q = fmaf(v, v, q); }
      #pragma unroll
      for (int off = 1; off < 16; off <<= 1) { s += __shfl_xor(s, off, 16); q += __shfl_xor(q, off, 16); }
      if (l15 == 0) { redS[wid][cf * 16 + l4 * 4 + r] = s; redQ[wid][cf * 16 + l4 * 4 + r] = q; }
    }
  __syncthreads();
  if (t < 128) {
    int wy2 = t >> 6, col = t & 63;
    int co = wy2 * 64 + col;
    float s = redS[wy2 * 2][col] + redS[wy2 * 2 + 1][col];
    float q = redQ[wy2 * 2][col] + redQ[wy2 * 2 + 1][col];
    long long pb = ((long long)(n * 64 + bx) * 128 + co) * 2;
    part[pb] = s; part[pb + 1] = q;
  }
}

// ---------------- BN reduce over 512 block-partials; blockIdx.y selects tensor ----------------
__global__ __launch_bounds__(256) void k_bnred(const float* __restrict__ pA, const float* __restrict__ pB,
                                               const float* __restrict__ gA, const float* __restrict__ gB,
                                               const float* __restrict__ bA, const float* __restrict__ bB,
                                               float* __restrict__ ssA, float* __restrict__ ssB) {
  int z = blockIdx.y;
  const float* part = z ? pB : pA;
  const float* g = z ? gB : gA;
  const float* bb = z ? bB : bA;
  float* ssout = z ? ssB : ssA;
  int c = blockIdx.x, t = threadIdx.x;
  float s = 0.f, q = 0.f;
  for (int b = t; b < 512; b += 256) {
    s += part[((long long)b * 128 + c) * 2];
    q += part[((long long)b * 128 + c) * 2 + 1];
  }
  __shared__ float r1[256], r2[256];
  r1[t] = s; r2[t] = q; __syncthreads();
  for (int o = 128; o > 0; o >>= 1) { if (t < o) { r1[t] += r1[t + o]; r2[t] += r2[t + o]; } __syncthreads(); }
  if (t == 0) {
    float mean = r1[0] / 131072.f;
    float var = r2[0] / 131072.f - mean * mean;
    float sc = g[c] * rsqrtf(var + 1e-5f);
    ssout[c] = sc;
    ssout[128 + c] = bb[c] - mean * sc;
  }
}

// ---------------- cubic power-mean per (n,c); blockIdx.z selects tensor ----------------
__global__ __launch_bounds__(256) void k_power(const float* __restrict__ in0, const float* __restrict__ in1,
                                               const float* __restrict__ ss0, const float* __restrict__ ss1,
                                               float* __restrict__ dst) {
  int z = blockIdx.z;
  const float* in = z ? in1 : in0;
  const float* ss = z ? ss1 : ss0;
  int c = blockIdx.x, n = blockIdx.y, t = threadIdx.x;
  float sc = ss[c], sh = ss[128 + c];
  long long base = (long long)(n * 128 + c) * HW;
  float s = 0.f;
  for (int i = t; i < HW; i += 256) {
    float r = fmaxf(fmaf(in[base + i], sc, sh), 0.f);
    s += r * r * r;
  }
  __shared__ float red[256];
  red[t] = s; __syncthreads();
  for (int o = 128; o > 0; o >>= 1) { if (t < o) red[t] += red[t + o]; __syncthreads(); }
  if (t == 0) dst[n * 256 + 2 * c + z] = cbrtf(red[0] * (1.f / 16384.f) + 1e-12f);
}

// ---------------- 1d conv x2 + sigmoid ----------------
__global__ __launch_bounds__(256) void k_dvec(const float* __restrict__ din, const float* __restrict__ c1,
                                              const float* __restrict__ c2, float* __restrict__ d0,
                                              float* __restrict__ d1) {
  __shared__ float a[256], b[256];
  int n = blockIdx.x, t = threadIdx.x;
  a[t] = din[n * 256 + t];
  __syncthreads();
  float acc = 0.f;
  #pragma unroll
  for (int k = 0; k < 5; ++k) { int j = t + k - 2; if (0 <= j && j < 256) acc = fmaf(c1[k], a[j], acc); }
  b[t] = acc; __syncthreads();
  float acc2 = 0.f;
  #pragma unroll
  for (int k = 0; k < 5; ++k) { int j = t + k - 2; if (0 <= j && j < 256) acc2 = fmaf(c2[k], b[j], acc2); }
  float sg = 1.f / (1.f + expf(-acc2));
  if ((t & 1) == 0) d0[n * 128 + (t >> 1)] = sg; else d1[n * 128 + (t >> 1)] = sg;
}

// ---------------- fused fmix + NHWC bf16 pack ----------------
__global__ __launch_bounds__(256) void k_fmixT(const float* __restrict__ low, const float* __restrict__ high,
                                               const float* __restrict__ ssl, const float* __restrict__ ssh,
                                               const float* __restrict__ d0, const float* __restrict__ d1,
                                               unsigned short* __restrict__ outT) {
  __shared__ float ld[64 * 129];
  int t = threadIdx.x;
  int h = blockIdx.x, n = blockIdx.y;
  const long long sb = (long long)n * 128 * HW + h * 128;
  unsigned short* dst = outT + (long long)n * NHWC_N + ((long long)(h + 1) * 130 + 1) * 128;
  for (int half = 0; half < 2; ++half) {
    __syncthreads();
    for (int e = t; e < 8192; e += 256) {
      int c = e >> 7, w = e & 127;
      int cg = half * 64 + c;
      float xl = fmaxf(fmaf(low[sb + (long long)cg * HW + w], ssl[cg], ssl[128 + cg]), 0.f);
      float xh = fmaxf(fmaf(high[sb + (long long)cg * HW + w], ssh[cg], ssh[128 + cg]), 0.f);
      ld[c * 129 + w] = d0[n * 128 + cg] * xl + d1[n * 128 + cg] * xh;
    }
    __syncthreads();
    for (int q = t; q < 1024; q += 256) {
      int w = q >> 3, cg8 = q & 7;
      bf16x8 pk;
      #pragma unroll
      for (int u = 0; u < 8; ++u) pk[u] = (short)f2b(ld[(cg8 * 8 + u) * 129 + w]);
      *(bf16x8*)(dst + (long long)w * 128 + half * 64 + cg8 * 8) = pk;
    }
  }
}

static void make_taps(int ks, double sigma, Taps* tp) {
  double c = (ks - 1) / 2.0, sum = 0.0, v[7];
  for (int i = 0; i < ks; ++i) { double d = i - c; v[i] = std::exp(-d * d / (2.0 * sigma * sigma)); sum += v[i]; }
  for (int i = 0; i < 7; ++i) tp->g[i] = (i < ks) ? (float)(v[i] / sum) : 0.f;
}

extern "C" void kernel_launch(void* const* d_in, const int* in_sizes, int n_in,
                              void* d_out, int out_size, void* d_ws, size_t ws_size,
                              hipStream_t stream) {
  const float* x         = (const float*)d_in[0];
  const float* dwconv_w  = (const float*)d_in[1];
  const float* dwconv_b  = (const float*)d_in[2];
  const float* qkvl_w    = (const float*)d_in[3];
  const float* qkvl_b    = (const float*)d_in[4];
  const float* reproj_w  = (const float*)d_in[5];
  const float* reproj_b  = (const float*)d_in[6];
  const float* queries_w = (const float*)d_in[7];
  const float* queries_b = (const float*)d_in[8];
  const float* sff_low_w = (const float*)d_in[9];
  const float* sff_low_g = (const float*)d_in[10];
  const float* sff_low_b = (const float*)d_in[11];
  const float* sff_high_w= (const float*)d_in[12];
  const float* sff_high_g= (const float*)d_in[13];
  const float* sff_high_b= (const float*)d_in[14];
  const float* sff_c1_w  = (const float*)d_in[15];
  const float* sff_c2_w  = (const float*)d_in[16];
  const float* out_conv_w= (const float*)d_in[17];
  const float* out_bn_g  = (const float*)d_in[18];
  const float* out_bn_b  = (const float*)d_in[19];
  const float* out_proj_w= (const float*)d_in[20];
  const float* out_proj_b= (const float*)d_in[21];
  float* ws  = (float*)d_ws;
  float* out = (float*)d_out;

  float* x1   = ws + OFF_X1;
  float* qs   = ws + OFF_QS;
  float* kk   = ws + OFF_KK;
  float* x2o  = ws + OFF_X2O;
  float* vv   = ws + OFF_V;
  float* lf   = ws + OFF_LF;
  float* qp   = ws + OFF_QP;
  float* kp   = ws + OFF_KP;
  float* ctx  = ws + U;
  float* attp = ws;
  float* qx   = ws;
  float* lowc = ws;
  float* highc= ws + U;
  float* ybuf = ws;             // B1 (lowc dead after fmixT)
  float* qkb  = ws + OFF_QKB;
  float* Abuf = ws + OFF_AA;
  float* Mq   = ws + OFF_MQ;
  float* Dq   = ws + OFF_DQ;
  float* pm   = ws + OFF_PMAX;
  float* psv  = ws + OFF_PSUM;
  float* Mc   = ws + OFF_MC;
  float* Dc   = ws + OFF_DC;
  float* att  = ws + OFF_ATT;
  float* ssl  = ws + OFF_SSL;
  float* ssh  = ws + OFF_SSH;
  float* ssy  = ws + OFF_SSY;
  float* dv   = ws + OFF_DV;
  float* d0v  = ws + OFF_D0;
  float* d1v  = ws + OFF_D1;
  unsigned short* wqk   = (unsigned short*)(ws + OFF_WQK);
  unsigned short* wlow  = (unsigned short*)(ws + OFF_WLOW);
  unsigned short* whigh = (unsigned short*)(ws + OFF_WHIGH);
  unsigned short* wout  = (unsigned short*)(ws + OFF_WOUT);
  unsigned short* effT  = (unsigned short*)out;      // d_out NHWC bf16 (front 34.6MB)
  unsigned short* freqT = (unsigned short*)(ws + U); // B2 front
  unsigned short* fT    = (unsigned short*)out;      // reuses effT region (halo already zero)
  float* ctxp  = out + DOFF_CTXP;                    // d_out tail scratch
  float* partA = out + DOFF_PARTA;
  float* partB = out + DOFF_PARTB;

  Taps t3, t5, t7;
  const double s3 = std::pow(2.0, 1.0 / 3.0);
  make_taps(3, 1.6, &t3);
  make_taps(5, 1.6 * s3, &t5);
  make_taps(7, 1.6 * s3 * s3, &t7);

  dim3 b256(256), b128(128);

  // ---- phase 1: eff -> effT ----
  k_wpackq<<<dim3(40), b256, 0, stream>>>(qkvl_w, wqk);
  k_haloz<<<dim3(258), b256, 0, stream>>>(effT);
  k_dwconv<<<dim3(32768), b256, 0, stream>>>(x, dwconv_w, dwconv_b, x1);
  k_qkvlm<<<dim3(256, 8), b256, 0, stream>>>(x, wqk, qkvl_b, qs, kk, vv, lf);
  k_pool<<<dim3(8192), b256, 0, stream>>>(qs, kk, qp, kp);
  k_qk<<<dim3(32, 8), b256, 0, stream>>>(qp, kp, qkb);
  k_qksm<<<dim3(8), dim3(32), 0, stream>>>(qkb, Abuf);
  k_x2o<<<dim3(512), b256, 0, stream>>>(Abuf, vv, x2o);
  k_gemm1x1m<M_EFF><<<dim3(128, 8), b256, 0, stream>>>(reproj_w, x1, lf, x2o, reproj_b,
                                                       nullptr, nullptr, nullptr, nullptr, effT);
  // ---- phase 2: ctx / att ----
  k_blur3<<<dim3(4, 1024), b256, 0, stream>>>(x, ctx, ctxp, t3, t5, t7);
  k_ctx_red<<<dim3(4), b256, 0, stream>>>(ctxp, Mc, Dc);
  k_attm<<<dim3(32, 8), b256, 0, stream>>>(ctx, Mc, Dc, attp);
  k_attred<<<dim3(512), b256, 0, stream>>>(attp, att);
  // ---- phase 3: qx -> freqT ----
  k_gemm1x1m<M_QX><<<dim3(128, 8), b256, 0, stream>>>(queries_w, x, nullptr, nullptr, queries_b,
                                                      nullptr, nullptr, nullptr, nullptr, qx);
  k_qx_stat1<<<dim3(128, 8), b128, 0, stream>>>(qx, pm, psv);
  k_qx_stat2<<<dim3(8), b128, 0, stream>>>(pm, psv, Mq, Dq);
  k_wpack<<<dim3(576, 3), b256, 0, stream>>>(sff_low_w, sff_high_w, out_conv_w, wlow, whigh, wout);
  k_haloz<<<dim3(258), b256, 0, stream>>>(freqT);
  k_gemm1x1m<M_FREQ><<<dim3(128, 8), b256, 0, stream>>>(att, qx, nullptr, nullptr, nullptr,
                                                        nullptr, Mq, Dq, x, freqT);
  // ---- phase 4: convs (+fused BN partials) / power / mix / out ----
  k_conv3l<<<dim3(64, 8, 2), b256, 0, stream>>>(freqT, effT, wlow, whigh, lowc, highc, partA, partB);
  k_bnred<<<dim3(128, 2), b256, 0, stream>>>(partA, partB, sff_low_g, sff_high_g,
                                             sff_low_b, sff_high_b, ssl, ssh);
  k_power<<<dim3(128, 8, 2), b256, 0, stream>>>(lowc, highc, ssl, ssh, dv);
  k_dvec<<<dim3(8), b256, 0, stream>>>(dv, sff_c1_w, sff_c2_w, d0v, d1v);
  k_fmixT<<<dim3(128, 8), b256, 0, stream>>>(lowc, highc, ssl, ssh, d0v, d1v, fT);
  k_conv3l<<<dim3(64, 8, 1), b256, 0, stream>>>(fT, fT, wout, wout, ybuf, ybuf, partA, partA);
  k_bnred<<<dim3(128, 1), b256, 0, stream>>>(partA, partA, out_bn_g, out_bn_g,
                                             out_bn_b, out_bn_b, ssy, ssy);
  k_gemm1x1m<M_OUT><<<dim3(128, 8), b256, 0, stream>>>(out_proj_w, ybuf, nullptr, nullptr, out_proj_b,
                                                       ssy, nullptr, nullptr, nullptr, out);
  (void)in_sizes; (void)n_in; (void)out_size; (void)ws_size;
}